// Round 2
// baseline (255.113 us; speedup 1.0000x reference)
//
#include <hip/hip_runtime.h>
#include <cstdint>

typedef unsigned short u16;
typedef __attribute__((ext_vector_type(4))) float f32x4;
typedef __attribute__((ext_vector_type(8))) short bf16x8;
typedef __attribute__((ext_vector_type(4))) u16 u16x4;

#define B_C 2
#define T_C 2048
#define H_C 16
#define KV_C 4
#define NQKV_C 1536

__device__ __forceinline__ u16 f2bf(float f) {
  unsigned u = __builtin_bit_cast(unsigned, f);
  u = (u + 0x7fffu + ((u >> 16) & 1u)) >> 16;
  return (u16)u;
}

// ---------- x: fp32 -> bf16 ----------
__global__ void k_cvt(const float* __restrict__ in, u16* __restrict__ out, int n4) {
  int i = blockIdx.x * blockDim.x + threadIdx.x;
  if (i >= n4) return;
  f32x4 v = *(const f32x4*)(in + (size_t)i * 4);
  u16x4 o;
  o[0] = f2bf(v[0]); o[1] = f2bf(v[1]); o[2] = f2bf(v[2]); o[3] = f2bf(v[3]);
  *(u16x4*)(out + (size_t)i * 4) = o;
}

// ---------- transpose fp32 [K][N] -> bf16 [N][K] ----------
__global__ void k_tr(const float* __restrict__ in, u16* __restrict__ out, int K, int N) {
  __shared__ float t[32][33];
  int kb = blockIdx.x * 32, nb = blockIdx.y * 32;
  int tx = threadIdx.x & 31, ty = threadIdx.x >> 5;
#pragma unroll
  for (int i = 0; i < 32; i += 8) t[ty + i][tx] = in[(size_t)(kb + ty + i) * N + nb + tx];
  __syncthreads();
#pragma unroll
  for (int i = 0; i < 32; i += 8) out[(size_t)(nb + ty + i) * K + kb + tx] = f2bf(t[tx][ty + i]);
}

// ---------- transpose bf16 [T][64] -> [64][T] per (b,kv) ----------
__global__ void k_trv(const u16* __restrict__ in, u16* __restrict__ out) {
  __shared__ u16 t[32][33];
  int tb = blockIdx.x * 32, db = blockIdx.y * 32, bh = blockIdx.z;
  const u16* src = in + (size_t)bh * T_C * 64;
  u16* dst = out + (size_t)bh * T_C * 64;
  int tx = threadIdx.x & 31, ty = threadIdx.x >> 5;
#pragma unroll
  for (int i = 0; i < 32; i += 8) t[ty + i][tx] = src[(size_t)(tb + ty + i) * 64 + db + tx];
  __syncthreads();
#pragma unroll
  for (int i = 0; i < 32; i += 8) dst[(size_t)(db + ty + i) * T_C + tb + tx] = t[tx][ty + i];
}

// ---------- GEMM: C[M][N] fp32 = A[M][K]bf16 * Bt[N][K]bf16^T ----------
__global__ __launch_bounds__(256, 2) void k_gemm_bt(
    const u16* __restrict__ A, const u16* __restrict__ Bt, float* __restrict__ C,
    int M, int N, int K) {
  constexpr int BK = 32;
  __shared__ u16 As[128 * BK];
  __shared__ u16 Bs[128 * BK];
  const int tid = threadIdx.x;
  const int lane = tid & 63, wid = tid >> 6;
  const int wr = wid >> 1, wc = wid & 1;
  const int l15 = lane & 15, lhi = lane >> 4;
  const int bm = blockIdx.x * 128, bn = blockIdx.y * 128;
  const int srow = tid >> 2, scol = (tid & 3) * 8;
  const u16* ga = A + (size_t)(bm + srow) * K + scol;
  const u16* gb = Bt + (size_t)(bn + srow) * K + scol;
  f32x4 acc[4][4] = {};
  const int aoff = (wr * 64 + l15) * BK + lhi * 8;
  const int boff = (wc * 64 + l15) * BK + lhi * 8;
  for (int k0 = 0; k0 < K; k0 += BK) {
    __syncthreads();
    __builtin_amdgcn_global_load_lds((__attribute__((address_space(1))) void*)(ga + k0),
                                     (__attribute__((address_space(3))) void*)(&As[tid * 8]), 16, 0, 0);
    __builtin_amdgcn_global_load_lds((__attribute__((address_space(1))) void*)(ga + (size_t)64 * K + k0),
                                     (__attribute__((address_space(3))) void*)(&As[2048 + tid * 8]), 16, 0, 0);
    __builtin_amdgcn_global_load_lds((__attribute__((address_space(1))) void*)(gb + k0),
                                     (__attribute__((address_space(3))) void*)(&Bs[tid * 8]), 16, 0, 0);
    __builtin_amdgcn_global_load_lds((__attribute__((address_space(1))) void*)(gb + (size_t)64 * K + k0),
                                     (__attribute__((address_space(3))) void*)(&Bs[2048 + tid * 8]), 16, 0, 0);
    __syncthreads();
    bf16x8 af[4], bfr[4];
#pragma unroll
    for (int i = 0; i < 4; i++) af[i] = *(const bf16x8*)&As[aoff + i * 16 * BK];
#pragma unroll
    for (int j = 0; j < 4; j++) bfr[j] = *(const bf16x8*)&Bs[boff + j * 16 * BK];
#pragma unroll
    for (int i = 0; i < 4; i++)
#pragma unroll
      for (int j = 0; j < 4; j++)
        acc[i][j] = __builtin_amdgcn_mfma_f32_16x16x32_bf16(af[i], bfr[j], acc[i][j], 0, 0, 0);
  }
  const int crow0 = bm + wr * 64 + lhi * 4, ccol0 = bn + wc * 64 + l15;
#pragma unroll
  for (int i = 0; i < 4; i++)
#pragma unroll
    for (int j = 0; j < 4; j++)
#pragma unroll
      for (int r = 0; r < 4; r++)
        C[(size_t)(crow0 + i * 16 + r) * N + ccol0 + j * 16] = acc[i][j][r];
}

// ---------- RoPE + relayout (q scaled by SCALE*log2e for exp2 softmax) ----------
__global__ void k_rope(const float* __restrict__ qkv, u16* __restrict__ qb,
                       u16* __restrict__ kb, u16* __restrict__ vb) {
  const int QP = B_C * H_C * T_C * 32;   // 2097152
  const int KP = B_C * KV_C * T_C * 32;  // 524288
  const int VN = B_C * KV_C * T_C * 64;  // 1048576
  int idx = blockIdx.x * blockDim.x + threadIdx.x;
  const float L2T = 13.28771237954945f;  // log2(10000)
  const float QS = 0.125f * 1.4426950408889634f;
  if (idx < QP) {
    int i = idx & 31, t = (idx >> 5) & 2047, h = (idx >> 16) & 15, b = idx >> 20;
    const float* src = qkv + (size_t)(b * T_C + t) * NQKV_C + h * 64 + 2 * i;
    float e = src[0], o = src[1];
    float ang = (float)t * exp2f(-(float)(2 * i) * (L2T / 64.0f));
    float sn, cs; sincosf(ang, &sn, &cs);
    size_t ob = ((size_t)((b * H_C + h) * T_C + t)) * 64 + 2 * i;
    qb[ob]     = f2bf((e * cs - o * sn) * QS);
    qb[ob + 1] = f2bf((e * sn + o * cs) * QS);
  } else if (idx < QP + KP) {
    int j = idx - QP;
    int i = j & 31, t = (j >> 5) & 2047, g = (j >> 16) & 3, b = j >> 18;
    const float* src = qkv + (size_t)(b * T_C + t) * NQKV_C + 1024 + g * 64 + 2 * i;
    float e = src[0], o = src[1];
    float ang = (float)t * exp2f(-(float)(2 * i) * (L2T / 64.0f));
    float sn, cs; sincosf(ang, &sn, &cs);
    size_t ob = ((size_t)((b * KV_C + g) * T_C + t)) * 64 + 2 * i;
    kb[ob]     = f2bf(e * cs - o * sn);
    kb[ob + 1] = f2bf(e * sn + o * cs);
  } else {
    int j = idx - QP - KP;
    if (j >= VN) return;
    int d = j & 63, t = (j >> 6) & 2047, g = (j >> 17) & 3, b = j >> 19;
    vb[((size_t)((b * KV_C + g) * T_C + t)) * 64 + d] =
        f2bf(qkv[(size_t)(b * T_C + t) * NQKV_C + 1280 + g * 64 + d]);
  }
}

// ---------- causal flash attention v2 ----------
// 128 q-rows/block, 4 waves x 32 rows (2 frag groups), KV tile 64.
// XOR-swizzled LDS (128B rows), reg-prefetched K/V (T14), heavy-first order.
__global__ __launch_bounds__(256, 3) void k_attn(
    const u16* __restrict__ q_bf, const u16* __restrict__ k_bf,
    const u16* __restrict__ vT_bf, u16* __restrict__ att_bf) {
  __shared__ u16 Ks[64 * 64];      // [key][d], swizzled
  __shared__ u16 Vt[64 * 64];      // [d][s], swizzled
  __shared__ u16 Ps[4][32 * 64];   // per-wave [q'][s], swizzled
  const int bid = blockIdx.x;
  const int qb = 15 - (bid >> 5);          // heavy-first
  const int hb = bid & 31;
  const int h = hb & 15, b = hb >> 4;
  const int kvh = h >> 2;
  const int tid = threadIdx.x, lane = tid & 63, w = tid >> 6;
  const int l15 = lane & 15, lhi = lane >> 4;
  const u16* Qg = q_bf + ((size_t)((b * H_C + h) * T_C) + qb * 128) * 64;
  const u16* Kg = k_bf + ((size_t)((b * KV_C + kvh) * T_C)) * 64;
  const u16* Vg = vT_bf + (size_t)(b * KV_C + kvh) * 64 * T_C;  // [64][T]

  // Q fragments: rows w*32 + g*16 + l15
  bf16x8 qf[2][2];
#pragma unroll
  for (int g = 0; g < 2; g++)
#pragma unroll
    for (int kc = 0; kc < 2; kc++)
      qf[g][kc] = *(const bf16x8*)&Qg[(size_t)(w * 32 + g * 16 + l15) * 64 + kc * 32 + lhi * 8];

  f32x4 o[2][4] = {};
  float m[2][4], lsum[2][4];
#pragma unroll
  for (int g = 0; g < 2; g++)
#pragma unroll
    for (int r = 0; r < 4; r++) { m[g][r] = -1e30f; lsum[g][r] = 0.f; }

  const int nt = 2 * (qb + 1);
  // staging geometry: chunk c in [0,512): row=c>>3, j=c&7 (16B chunks of 128B rows)
  const int c0 = tid, c1 = tid + 256;
  const int r0 = c0 >> 3, j0 = c0 & 7, r1 = c1 >> 3, j1 = c1 & 7;
  char* ksb = (char*)Ks;
  char* vtb = (char*)Vt;
  char* psb = (char*)Ps[w];
  const int wb0 = r0 * 128 + ((j0 * 16) ^ ((r0 & 7) << 4));
  const int wb1 = r1 * 128 + ((j1 * 16) ^ ((r1 & 7) << 4));

  bf16x8 kr0, kr1, vr0, vr1;
  // preload tile 0
  kr0 = *(const bf16x8*)&Kg[(size_t)r0 * 64 + j0 * 8];
  kr1 = *(const bf16x8*)&Kg[(size_t)r1 * 64 + j1 * 8];
  vr0 = *(const bf16x8*)&Vg[(size_t)r0 * T_C + j0 * 8];
  vr1 = *(const bf16x8*)&Vg[(size_t)r1 * T_C + j1 * 8];

  for (int it = 0; it < nt; ++it) {
    const int t0 = it * 64;
    __syncthreads();   // prior reads done; prefetch loads drained here
    *(bf16x8*)(ksb + wb0) = kr0;
    *(bf16x8*)(ksb + wb1) = kr1;
    *(bf16x8*)(vtb + wb0) = vr0;
    *(bf16x8*)(vtb + wb1) = vr1;
    __syncthreads();   // lgkm drained -> tile visible
    if (it + 1 < nt) {  // prefetch next tile during compute
      const int t1 = t0 + 64;
      kr0 = *(const bf16x8*)&Kg[(size_t)(t1 + r0) * 64 + j0 * 8];
      kr1 = *(const bf16x8*)&Kg[(size_t)(t1 + r1) * 64 + j1 * 8];
      vr0 = *(const bf16x8*)&Vg[(size_t)r0 * T_C + t1 + j0 * 8];
      vr1 = *(const bf16x8*)&Vg[(size_t)r1 * T_C + t1 + j1 * 8];
    }
    // ---- S = Q K^T ----
    bf16x8 kf[4][2];
#pragma unroll
    for (int nf = 0; nf < 4; nf++)
#pragma unroll
      for (int kc = 0; kc < 2; kc++) {
        const int row = nf * 16 + l15;
        kf[nf][kc] = *(const bf16x8*)(ksb + row * 128 + ((kc * 64 + lhi * 16) ^ ((l15 & 7) << 4)));
      }
    f32x4 s[2][4] = {};
#pragma unroll
    for (int g = 0; g < 2; g++)
#pragma unroll
      for (int nf = 0; nf < 4; nf++)
#pragma unroll
        for (int kc = 0; kc < 2; kc++)
          s[g][nf] = __builtin_amdgcn_mfma_f32_16x16x32_bf16(qf[g][kc], kf[nf][kc], s[g][nf], 0, 0, 0);
    // ---- causal mask (only near diagonal) ----
    if (it >= nt - 2) {
#pragma unroll
      for (int g = 0; g < 2; g++) {
        const int qg = qb * 128 + w * 32 + g * 16 + lhi * 4;
#pragma unroll
        for (int nf = 0; nf < 4; nf++) {
          const int key = t0 + nf * 16 + l15;
#pragma unroll
          for (int r = 0; r < 4; r++)
            if (key > qg + r) s[g][nf][r] = -1e30f;
        }
      }
    }
    // ---- online softmax (exp2 domain) ----
#pragma unroll
    for (int g = 0; g < 2; g++) {
      float tmax[4];
#pragma unroll
      for (int r = 0; r < 4; r++)
        tmax[r] = fmaxf(fmaxf(s[g][0][r], s[g][1][r]), fmaxf(s[g][2][r], s[g][3][r]));
#pragma unroll
      for (int x = 1; x < 16; x <<= 1)
#pragma unroll
        for (int r = 0; r < 4; r++) tmax[r] = fmaxf(tmax[r], __shfl_xor(tmax[r], x, 64));
      float alpha[4];
#pragma unroll
      for (int r = 0; r < 4; r++) {
        float mn = fmaxf(m[g][r], tmax[r]);
        alpha[r] = __builtin_exp2f(m[g][r] - mn);
        m[g][r] = mn;
      }
      float psum[4] = {0.f, 0.f, 0.f, 0.f};
#pragma unroll
      for (int nf = 0; nf < 4; nf++)
#pragma unroll
        for (int r = 0; r < 4; r++) {
          float p = __builtin_exp2f(s[g][nf][r] - m[g][r]);
          s[g][nf][r] = p;
          psum[r] += p;
        }
#pragma unroll
      for (int x = 1; x < 16; x <<= 1)
#pragma unroll
        for (int r = 0; r < 4; r++) psum[r] += __shfl_xor(psum[r], x, 64);
#pragma unroll
      for (int r = 0; r < 4; r++) lsum[g][r] = lsum[g][r] * alpha[r] + psum[r];
      // P -> per-wave LDS (swizzled [q'][s])
#pragma unroll
      for (int nf = 0; nf < 4; nf++)
#pragma unroll
        for (int r = 0; r < 4; r++) {
          const int q_ = g * 16 + lhi * 4 + r;
          *(u16*)(psb + q_ * 128 + ((nf * 32 + l15 * 2) ^ ((q_ & 7) << 4))) = f2bf(s[g][nf][r]);
        }
      // rescale O
#pragma unroll
      for (int nf = 0; nf < 4; nf++)
#pragma unroll
        for (int r = 0; r < 4; r++) o[g][nf][r] *= alpha[r];
    }
    asm volatile("s_waitcnt lgkmcnt(0)" ::: "memory");
    __builtin_amdgcn_sched_barrier(0);
    // ---- O += P V ----
#pragma unroll
    for (int g = 0; g < 2; g++)
#pragma unroll
      for (int kc = 0; kc < 2; kc++) {
        const int prow = g * 16 + l15;
        bf16x8 pa = *(const bf16x8*)(psb + prow * 128 + ((kc * 64 + lhi * 16) ^ ((l15 & 7) << 4)));
#pragma unroll
        for (int nf = 0; nf < 4; nf++) {
          bf16x8 vf = *(const bf16x8*)(vtb + (nf * 16 + l15) * 128 + ((kc * 64 + lhi * 16) ^ ((l15 & 7) << 4)));
          o[g][nf] = __builtin_amdgcn_mfma_f32_16x16x32_bf16(pa, vf, o[g][nf], 0, 0, 0);
        }
      }
  }
  // ---- epilogue ----
#pragma unroll
  for (int g = 0; g < 2; g++) {
    const int trow = qb * 128 + w * 32 + g * 16 + lhi * 4;
    const size_t obase = ((size_t)(b * T_C) + trow) * 1024 + h * 64;
#pragma unroll
    for (int nf = 0; nf < 4; nf++)
#pragma unroll
      for (int r = 0; r < 4; r++)
        att_bf[obase + (size_t)r * 1024 + nf * 16 + l15] = f2bf(o[g][nf][r] / lsum[g][r]);
  }
}

extern "C" void kernel_launch(void* const* d_in, const int* in_sizes, int n_in,
                              void* d_out, int out_size, void* d_ws, size_t ws_size,
                              hipStream_t stream) {
  const float* x  = (const float*)d_in[0];
  const float* wq = (const float*)d_in[2];
  const float* wk = (const float*)d_in[3];
  const float* wv = (const float*)d_in[4];
  const float* wo = (const float*)d_in[5];
  float* out = (float*)d_out;

  char* ws = (char*)d_ws;
  u16*   xb    = (u16*)(ws);                          //  8 MiB
  u16*   wqkvT = (u16*)(ws + (8ull  << 20));          //  3 MiB
  u16*   woT   = (u16*)(ws + (11ull << 20));          //  2 MiB
  float* qkv   = (float*)(ws + (13ull << 20));        // 24 MiB (freed after k_rope)
  u16*   vT_bf = (u16*)(ws + (13ull << 20));          //  2 MiB (reuses qkv region)
  u16*   q_bf  = (u16*)(ws + (37ull << 20));          //  8 MiB
  u16*   k_bf  = (u16*)(ws + (45ull << 20));          //  2 MiB
  u16*   v_bf  = (u16*)(ws + (47ull << 20));          //  2 MiB
  u16*   attb  = (u16*)(ws + (49ull << 20));          //  8 MiB

  k_cvt<<<4096, 256, 0, stream>>>(x, xb, 4096 * 1024 / 4);
  k_tr<<<dim3(32, 32), 256, 0, stream>>>(wq, wqkvT, 1024, 1024);
  k_tr<<<dim3(32, 8),  256, 0, stream>>>(wk, wqkvT + 1024 * 1024, 1024, 256);
  k_tr<<<dim3(32, 8),  256, 0, stream>>>(wv, wqkvT + 1280 * 1024, 1024, 256);
  k_tr<<<dim3(32, 32), 256, 0, stream>>>(wo, woT, 1024, 1024);
  k_gemm_bt<<<dim3(32, 12), 256, 0, stream>>>(xb, wqkvT, qkv, 4096, 1536, 1024);
  k_rope<<<14336, 256, 0, stream>>>(qkv, q_bf, k_bf, v_bf);
  k_trv<<<dim3(64, 2, 8), 256, 0, stream>>>(v_bf, vT_bf);
  k_attn<<<512, 256, 0, stream>>>(q_bf, k_bf, vT_bf, attb);
  k_gemm_bt<<<dim3(32, 8), 256, 0, stream>>>(attb, woT, out, 4096, 1024, 1024);
}

// Round 7
// 150.279 us; speedup vs baseline: 1.6976x; 1.6976x over previous
//
#include <hip/hip_runtime.h>
#include <cstdint>

typedef unsigned short u16;
typedef __attribute__((ext_vector_type(4))) float f32x4;
typedef __attribute__((ext_vector_type(8))) short bf16x8;
typedef __attribute__((ext_vector_type(4))) u16 u16x4;

#define B_C 2
#define T_C 2048
#define H_C 16
#define KV_C 4
#define NQKV_C 1536

__device__ __forceinline__ u16 f2bf(float f) {
  unsigned u = __builtin_bit_cast(unsigned, f);
  u = (u + 0x7fffu + ((u >> 16) & 1u)) >> 16;
  return (u16)u;
}

// ---------- x: fp32 -> bf16 ----------
__global__ void k_cvt(const float* __restrict__ in, u16* __restrict__ out, int n4) {
  int i = blockIdx.x * blockDim.x + threadIdx.x;
  if (i >= n4) return;
  f32x4 v = *(const f32x4*)(in + (size_t)i * 4);
  u16x4 o;
  o[0] = f2bf(v[0]); o[1] = f2bf(v[1]); o[2] = f2bf(v[2]); o[3] = f2bf(v[3]);
  *(u16x4*)(out + (size_t)i * 4) = o;
}

// ---------- transpose fp32 [K][N] -> bf16 [N][K] ----------
__global__ void k_tr(const float* __restrict__ in, u16* __restrict__ out, int K, int N) {
  __shared__ float t[32][33];
  int kb = blockIdx.x * 32, nb = blockIdx.y * 32;
  int tx = threadIdx.x & 31, ty = threadIdx.x >> 5;
#pragma unroll
  for (int i = 0; i < 32; i += 8) t[ty + i][tx] = in[(size_t)(kb + ty + i) * N + nb + tx];
  __syncthreads();
#pragma unroll
  for (int i = 0; i < 32; i += 8) out[(size_t)(nb + ty + i) * K + kb + tx] = f2bf(t[tx][ty + i]);
}

// ---------- transpose bf16 [T][64] -> [64][T] per (b,kv) ----------
__global__ void k_trv(const u16* __restrict__ in, u16* __restrict__ out) {
  __shared__ u16 t[32][33];
  int tb = blockIdx.x * 32, db = blockIdx.y * 32, bh = blockIdx.z;
  const u16* src = in + (size_t)bh * T_C * 64;
  u16* dst = out + (size_t)bh * T_C * 64;
  int tx = threadIdx.x & 31, ty = threadIdx.x >> 5;
#pragma unroll
  for (int i = 0; i < 32; i += 8) t[ty + i][tx] = src[(size_t)(tb + ty + i) * 64 + db + tx];
  __syncthreads();
#pragma unroll
  for (int i = 0; i < 32; i += 8) dst[(size_t)(db + ty + i) * T_C + tb + tx] = t[tx][ty + i];
}

// ---------- GEMM: C[M][N] fp32 = A[M][K]bf16 * Bt[N][K]bf16^T ----------
__global__ __launch_bounds__(256, 2) void k_gemm_bt(
    const u16* __restrict__ A, const u16* __restrict__ Bt, float* __restrict__ C,
    int M, int N, int K) {
  constexpr int BK = 32;
  __shared__ u16 As[128 * BK];
  __shared__ u16 Bs[128 * BK];
  const int tid = threadIdx.x;
  const int lane = tid & 63, wid = tid >> 6;
  const int wr = wid >> 1, wc = wid & 1;
  const int l15 = lane & 15, lhi = lane >> 4;
  const int bm = blockIdx.x * 128, bn = blockIdx.y * 128;
  const int srow = tid >> 2, scol = (tid & 3) * 8;
  const u16* ga = A + (size_t)(bm + srow) * K + scol;
  const u16* gb = Bt + (size_t)(bn + srow) * K + scol;
  f32x4 acc[4][4] = {};
  const int aoff = (wr * 64 + l15) * BK + lhi * 8;
  const int boff = (wc * 64 + l15) * BK + lhi * 8;
  for (int k0 = 0; k0 < K; k0 += BK) {
    __syncthreads();
    __builtin_amdgcn_global_load_lds((__attribute__((address_space(1))) void*)(ga + k0),
                                     (__attribute__((address_space(3))) void*)(&As[tid * 8]), 16, 0, 0);
    __builtin_amdgcn_global_load_lds((__attribute__((address_space(1))) void*)(ga + (size_t)64 * K + k0),
                                     (__attribute__((address_space(3))) void*)(&As[2048 + tid * 8]), 16, 0, 0);
    __builtin_amdgcn_global_load_lds((__attribute__((address_space(1))) void*)(gb + k0),
                                     (__attribute__((address_space(3))) void*)(&Bs[tid * 8]), 16, 0, 0);
    __builtin_amdgcn_global_load_lds((__attribute__((address_space(1))) void*)(gb + (size_t)64 * K + k0),
                                     (__attribute__((address_space(3))) void*)(&Bs[2048 + tid * 8]), 16, 0, 0);
    __syncthreads();
    bf16x8 af[4], bfr[4];
#pragma unroll
    for (int i = 0; i < 4; i++) af[i] = *(const bf16x8*)&As[aoff + i * 16 * BK];
#pragma unroll
    for (int j = 0; j < 4; j++) bfr[j] = *(const bf16x8*)&Bs[boff + j * 16 * BK];
#pragma unroll
    for (int i = 0; i < 4; i++)
#pragma unroll
      for (int j = 0; j < 4; j++)
        acc[i][j] = __builtin_amdgcn_mfma_f32_16x16x32_bf16(af[i], bfr[j], acc[i][j], 0, 0, 0);
  }
  const int crow0 = bm + wr * 64 + lhi * 4, ccol0 = bn + wc * 64 + l15;
#pragma unroll
  for (int i = 0; i < 4; i++)
#pragma unroll
    for (int j = 0; j < 4; j++)
#pragma unroll
      for (int r = 0; r < 4; r++)
        C[(size_t)(crow0 + i * 16 + r) * N + ccol0 + j * 16] = acc[i][j][r];
}

// ---------- RoPE + relayout (q scaled by SCALE*log2e for exp2 softmax) ----------
__global__ void k_rope(const float* __restrict__ qkv, u16* __restrict__ qb,
                       u16* __restrict__ kb, u16* __restrict__ vb) {
  const int QP = B_C * H_C * T_C * 32;   // 2097152
  const int KP = B_C * KV_C * T_C * 32;  // 524288
  const int VN = B_C * KV_C * T_C * 64;  // 1048576
  int idx = blockIdx.x * blockDim.x + threadIdx.x;
  const float L2T = 13.28771237954945f;  // log2(10000)
  const float QS = 0.125f * 1.4426950408889634f;
  if (idx < QP) {
    int i = idx & 31, t = (idx >> 5) & 2047, h = (idx >> 16) & 15, b = idx >> 20;
    const float* src = qkv + (size_t)(b * T_C + t) * NQKV_C + h * 64 + 2 * i;
    float e = src[0], o = src[1];
    float ang = (float)t * exp2f(-(float)(2 * i) * (L2T / 64.0f));
    float sn, cs; sincosf(ang, &sn, &cs);
    size_t ob = ((size_t)((b * H_C + h) * T_C + t)) * 64 + 2 * i;
    qb[ob]     = f2bf((e * cs - o * sn) * QS);
    qb[ob + 1] = f2bf((e * sn + o * cs) * QS);
  } else if (idx < QP + KP) {
    int j = idx - QP;
    int i = j & 31, t = (j >> 5) & 2047, g = (j >> 16) & 3, b = j >> 18;
    const float* src = qkv + (size_t)(b * T_C + t) * NQKV_C + 1024 + g * 64 + 2 * i;
    float e = src[0], o = src[1];
    float ang = (float)t * exp2f(-(float)(2 * i) * (L2T / 64.0f));
    float sn, cs; sincosf(ang, &sn, &cs);
    size_t ob = ((size_t)((b * KV_C + g) * T_C + t)) * 64 + 2 * i;
    kb[ob]     = f2bf(e * cs - o * sn);
    kb[ob + 1] = f2bf(e * sn + o * cs);
  } else {
    int j = idx - QP - KP;
    if (j >= VN) return;
    int d = j & 63, t = (j >> 6) & 2047, g = (j >> 17) & 3, b = j >> 19;
    vb[((size_t)((b * KV_C + g) * T_C + t)) * 64 + d] =
        f2bf(qkv[(size_t)(b * T_C + t) * NQKV_C + 1280 + g * 64 + d]);
  }
}

// ---------- causal flash attention v3 ----------
// 64 q-rows/block (1024 blocks = 4/CU), KV tile 64, double-buffered LDS,
// ONE barrier/iter, prefetch-before-compute, XOR swizzle, setprio on MFMA.
__global__ __launch_bounds__(256, 4) void k_attn(
    const u16* __restrict__ q_bf, const u16* __restrict__ k_bf,
    const u16* __restrict__ vT_bf, u16* __restrict__ att_bf) {
  // LDS map: [0x0000) K buf0 | [0x2000) K buf1 | [0x4000) V^T buf0 |
  //          [0x6000) V^T buf1 | [0x8000) P: 2KB per wave.  Total 40 KB.
  __shared__ __align__(16) char lds[40960];
  const int bid = blockIdx.x;
  const int g = bid >> 5, g0 = g & 7, gs = g >> 3;
  // balanced heavy-first qb map: per-CU sets {31-g0, g0, 23-g0, 8+g0} sum to 66 iters
  const int qb = (gs == 0) ? (31 - g0) : (gs == 1) ? g0 : (gs == 2) ? (23 - g0) : (8 + g0);
  const int hb = bid & 31;
  const int h = hb & 15, b = hb >> 4;
  const int kvh = h >> 2;
  const int tid = threadIdx.x, lane = tid & 63, w = tid >> 6;
  const int l15 = lane & 15, lhi = lane >> 4;
  const u16* Qg = q_bf + ((size_t)((b * H_C + h) * T_C) + qb * 64) * 64;
  const u16* Kg = k_bf + ((size_t)((b * KV_C + kvh) * T_C)) * 64;
  const u16* Vg = vT_bf + (size_t)(b * KV_C + kvh) * 64 * T_C;  // [64][T]

  bf16x8 qf[2];
  const int qrow = w * 16 + l15;
#pragma unroll
  for (int kc = 0; kc < 2; kc++)
    qf[kc] = *(const bf16x8*)&Qg[(size_t)qrow * 64 + kc * 32 + lhi * 8];

  f32x4 o[4] = {};
  float m[4], lsum[4];
#pragma unroll
  for (int r = 0; r < 4; r++) { m[r] = -1e30f; lsum[r] = 0.f; }

  const int nt = qb + 1;
  // staging: 8KB tile = 512 x 16B chunks; thread handles rows r0 (0..31), r1 (32..63)
  const int r0 = tid >> 3, j0 = tid & 7;
  const int r1 = r0 + 32;
  const int wb0 = r0 * 128 + ((j0 * 16) ^ ((r0 & 7) << 4));
  const int wb1 = r1 * 128 + ((j0 * 16) ^ ((r1 & 7) << 4));
  char* psb = lds + 0x8000 + w * 0x800;

  bf16x8 kr0, kr1, vr0, vr1;
  // prologue: tile 0 -> buf0
  kr0 = *(const bf16x8*)&Kg[(size_t)r0 * 64 + j0 * 8];
  kr1 = *(const bf16x8*)&Kg[(size_t)r1 * 64 + j0 * 8];
  vr0 = *(const bf16x8*)&Vg[(size_t)r0 * T_C + j0 * 8];
  vr1 = *(const bf16x8*)&Vg[(size_t)r1 * T_C + j0 * 8];
  *(bf16x8*)(lds + wb0) = kr0;
  *(bf16x8*)(lds + wb1) = kr1;
  *(bf16x8*)(lds + 0x4000 + wb0) = vr0;
  *(bf16x8*)(lds + 0x4000 + wb1) = vr1;
  __syncthreads();

  for (int it = 0; it < nt; ++it) {
    const int t0 = it * 64;
    const int coff = (it & 1) * 0x2000;
    if (it + 1 < nt) {  // prefetch next tile (hides under compute)
      const int t1 = t0 + 64;
      kr0 = *(const bf16x8*)&Kg[(size_t)(t1 + r0) * 64 + j0 * 8];
      kr1 = *(const bf16x8*)&Kg[(size_t)(t1 + r1) * 64 + j0 * 8];
      vr0 = *(const bf16x8*)&Vg[(size_t)r0 * T_C + t1 + j0 * 8];
      vr1 = *(const bf16x8*)&Vg[(size_t)r1 * T_C + t1 + j0 * 8];
    }
    // ---- S = Q K^T ----
    bf16x8 kf[4][2];
#pragma unroll
    for (int nf = 0; nf < 4; nf++)
#pragma unroll
      for (int kc = 0; kc < 2; kc++) {
        const int row = nf * 16 + l15;
        kf[nf][kc] = *(const bf16x8*)(lds + coff + row * 128 +
                                      ((kc * 64 + lhi * 16) ^ ((l15 & 7) << 4)));
      }
    f32x4 s[4] = {};
    __builtin_amdgcn_s_setprio(1);
#pragma unroll
    for (int nf = 0; nf < 4; nf++)
#pragma unroll
      for (int kc = 0; kc < 2; kc++)
        s[nf] = __builtin_amdgcn_mfma_f32_16x16x32_bf16(qf[kc], kf[nf][kc], s[nf], 0, 0, 0);
    __builtin_amdgcn_s_setprio(0);
    // ---- causal mask on diagonal tile ----
    if (it == nt - 1) {
      const int qg = qb * 64 + w * 16 + lhi * 4;
#pragma unroll
      for (int nf = 0; nf < 4; nf++) {
        const int key = t0 + nf * 16 + l15;
#pragma unroll
        for (int r = 0; r < 4; r++)
          if (key > qg + r) s[nf][r] = -1e30f;
      }
    }
    // ---- online softmax (exp2 domain; q pre-scaled by log2e) ----
    float tmax[4];
#pragma unroll
    for (int r = 0; r < 4; r++)
      tmax[r] = fmaxf(fmaxf(s[0][r], s[1][r]), fmaxf(s[2][r], s[3][r]));
#pragma unroll
    for (int x = 1; x < 16; x <<= 1)
#pragma unroll
      for (int r = 0; r < 4; r++) tmax[r] = fmaxf(tmax[r], __shfl_xor(tmax[r], x, 64));
    float alpha[4];
#pragma unroll
    for (int r = 0; r < 4; r++) {
      float mn = fmaxf(m[r], tmax[r]);
      alpha[r] = __builtin_exp2f(m[r] - mn);
      m[r] = mn;
    }
    float psum[4] = {0.f, 0.f, 0.f, 0.f};
#pragma unroll
    for (int nf = 0; nf < 4; nf++)
#pragma unroll
      for (int r = 0; r < 4; r++) {
        float p = __builtin_exp2f(s[nf][r] - m[r]);
        s[nf][r] = p;
        psum[r] += p;
      }
#pragma unroll
    for (int x = 1; x < 16; x <<= 1)
#pragma unroll
      for (int r = 0; r < 4; r++) psum[r] += __shfl_xor(psum[r], x, 64);
#pragma unroll
    for (int r = 0; r < 4; r++) lsum[r] = lsum[r] * alpha[r] + psum[r];
    // ---- P -> per-wave LDS (swizzled) ----
#pragma unroll
    for (int nf = 0; nf < 4; nf++)
#pragma unroll
      for (int r = 0; r < 4; r++) {
        const int q_ = lhi * 4 + r;
        *(u16*)(psb + q_ * 128 + ((nf * 32 + l15 * 2) ^ ((q_ & 7) << 4))) = f2bf(s[nf][r]);
      }
    // rescale O while P-writes drain
#pragma unroll
    for (int nf = 0; nf < 4; nf++)
#pragma unroll
      for (int r = 0; r < 4; r++) o[nf][r] *= alpha[r];
    asm volatile("s_waitcnt lgkmcnt(0)" ::: "memory");
    __builtin_amdgcn_sched_barrier(0);
    // ---- O += P V ----
    __builtin_amdgcn_s_setprio(1);
#pragma unroll
    for (int kc = 0; kc < 2; kc++) {
      bf16x8 pa = *(const bf16x8*)(psb + l15 * 128 +
                                   ((kc * 64 + lhi * 16) ^ ((l15 & 7) << 4)));
#pragma unroll
      for (int nf = 0; nf < 4; nf++) {
        bf16x8 vf = *(const bf16x8*)(lds + 0x4000 + coff + (nf * 16 + l15) * 128 +
                                     ((kc * 64 + lhi * 16) ^ ((l15 & 7) << 4)));
        o[nf] = __builtin_amdgcn_mfma_f32_16x16x32_bf16(pa, vf, o[nf], 0, 0, 0);
      }
    }
    __builtin_amdgcn_s_setprio(0);
    // ---- write next tile into other buffer ----
    if (it + 1 < nt) {
      const int noff = ((it + 1) & 1) * 0x2000;
      *(bf16x8*)(lds + noff + wb0) = kr0;
      *(bf16x8*)(lds + noff + wb1) = kr1;
      *(bf16x8*)(lds + 0x4000 + noff + wb0) = vr0;
      *(bf16x8*)(lds + 0x4000 + noff + wb1) = vr1;
    }
    __syncthreads();
  }
  // ---- epilogue ----
  float inv[4];
#pragma unroll
  for (int r = 0; r < 4; r++) inv[r] = 1.0f / lsum[r];
  const int trow = qb * 64 + w * 16 + lhi * 4;
  const size_t obase = ((size_t)(b * T_C) + trow) * 1024 + h * 64;
#pragma unroll
  for (int nf = 0; nf < 4; nf++)
#pragma unroll
    for (int r = 0; r < 4; r++)
      att_bf[obase + (size_t)r * 1024 + nf * 16 + l15] = f2bf(o[nf][r] * inv[r]);
}

extern "C" void kernel_launch(void* const* d_in, const int* in_sizes, int n_in,
                              void* d_out, int out_size, void* d_ws, size_t ws_size,
                              hipStream_t stream) {
  const float* x  = (const float*)d_in[0];
  const float* wq = (const float*)d_in[2];
  const float* wk = (const float*)d_in[3];
  const float* wv = (const float*)d_in[4];
  const float* wo = (const float*)d_in[5];
  float* out = (float*)d_out;

  char* ws = (char*)d_ws;
  u16*   xb    = (u16*)(ws);                          //  8 MiB
  u16*   wqkvT = (u16*)(ws + (8ull  << 20));          //  3 MiB
  u16*   woT   = (u16*)(ws + (11ull << 20));          //  2 MiB
  float* qkv   = (float*)(ws + (13ull << 20));        // 24 MiB (freed after k_rope)
  u16*   vT_bf = (u16*)(ws + (13ull << 20));          //  2 MiB (reuses qkv region)
  u16*   q_bf  = (u16*)(ws + (37ull << 20));          //  8 MiB
  u16*   k_bf  = (u16*)(ws + (45ull << 20));          //  2 MiB
  u16*   v_bf  = (u16*)(ws + (47ull << 20));          //  2 MiB
  u16*   attb  = (u16*)(ws + (49ull << 20));          //  8 MiB

  k_cvt<<<4096, 256, 0, stream>>>(x, xb, 4096 * 1024 / 4);
  k_tr<<<dim3(32, 32), 256, 0, stream>>>(wq, wqkvT, 1024, 1024);
  k_tr<<<dim3(32, 8),  256, 0, stream>>>(wk, wqkvT + 1024 * 1024, 1024, 256);
  k_tr<<<dim3(32, 8),  256, 0, stream>>>(wv, wqkvT + 1280 * 1024, 1024, 256);
  k_tr<<<dim3(32, 32), 256, 0, stream>>>(wo, woT, 1024, 1024);
  k_gemm_bt<<<dim3(32, 12), 256, 0, stream>>>(xb, wqkvT, qkv, 4096, 1536, 1024);
  k_rope<<<14336, 256, 0, stream>>>(qkv, q_bf, k_bf, v_bf);
  k_trv<<<dim3(64, 2, 8), 256, 0, stream>>>(v_bf, vT_bf);
  k_attn<<<1024, 256, 0, stream>>>(q_bf, k_bf, vT_bf, attb);
  k_gemm_bt<<<dim3(32, 8), 256, 0, stream>>>(attb, woT, out, 4096, 1024, 1024);
}

// Round 8
// 131.530 us; speedup vs baseline: 1.9396x; 1.1425x over previous
//
#include <hip/hip_runtime.h>
#include <cstdint>

typedef unsigned short u16;
typedef __attribute__((ext_vector_type(2))) float f32x2;
typedef __attribute__((ext_vector_type(4))) float f32x4;
typedef __attribute__((ext_vector_type(8))) short bf16x8;
typedef __attribute__((ext_vector_type(4))) u16 u16x4;

#define B_C 2
#define T_C 2048
#define H_C 16
#define KV_C 4

__device__ __forceinline__ u16 f2bf(float f) {
  unsigned u = __builtin_bit_cast(unsigned, f);
  u = (u + 0x7fffu + ((u >> 16) & 1u)) >> 16;
  return (u16)u;
}

// ---------- x: fp32 -> bf16 ----------
__global__ void k_cvt(const float* __restrict__ in, u16* __restrict__ out, int n4) {
  int i = blockIdx.x * blockDim.x + threadIdx.x;
  if (i >= n4) return;
  f32x4 v = *(const f32x4*)(in + (size_t)i * 4);
  u16x4 o;
  o[0] = f2bf(v[0]); o[1] = f2bf(v[1]); o[2] = f2bf(v[2]); o[3] = f2bf(v[3]);
  *(u16x4*)(out + (size_t)i * 4) = o;
}

// ---------- transpose fp32 [K][N] -> bf16 [N][K] ----------
__global__ void k_tr(const float* __restrict__ in, u16* __restrict__ out, int K, int N) {
  __shared__ float t[32][33];
  int kb = blockIdx.x * 32, nb = blockIdx.y * 32;
  int tx = threadIdx.x & 31, ty = threadIdx.x >> 5;
#pragma unroll
  for (int i = 0; i < 32; i += 8) t[ty + i][tx] = in[(size_t)(kb + ty + i) * N + nb + tx];
  __syncthreads();
#pragma unroll
  for (int i = 0; i < 32; i += 8) out[(size_t)(nb + ty + i) * K + kb + tx] = f2bf(t[tx][ty + i]);
}

// ---------- RoPE cos/sin table [2048][32] ----------
__global__ void k_costab(f32x2* __restrict__ tab) {
  int idx = blockIdx.x * 256 + threadIdx.x;  // t*32 + i
  int i = idx & 31, t = idx >> 5;
  float ang = (float)t * exp2f(-(float)(2 * i) * (13.28771237954945f / 64.0f));
  float sn, cs; sincosf(ang, &sn, &cs);
  f32x2 v; v.x = cs; v.y = sn;
  tab[idx] = v;
}

// ---------- GEMM1: x @ wqkvT with fused RoPE + relayout epilogue ----------
// A [4096][1024] bf16, Bt [1536][1024] bf16. Writes q_bf [2][16][2048][64],
// k_bf [2][4][2048][64], vT_bf [2][4][64][2048] directly (bf16).
__global__ __launch_bounds__(256, 2) void k_gemm_qkv(
    const u16* __restrict__ A, const u16* __restrict__ Bt,
    const f32x2* __restrict__ tab,
    u16* __restrict__ qb_, u16* __restrict__ kb_, u16* __restrict__ vT_) {
  constexpr int BK = 32, K = 1024;
  __shared__ u16 As[128 * BK];
  __shared__ u16 Bs[128 * BK];
  const int tid = threadIdx.x;
  const int lane = tid & 63, wid = tid >> 6;
  const int wr = wid >> 1, wc = wid & 1;
  const int l15 = lane & 15, lhi = lane >> 4;
  const int bm = blockIdx.x * 128, bn = blockIdx.y * 128;
  const int srow = tid >> 2, scol = (tid & 3) * 8;
  const u16* ga = A + (size_t)(bm + srow) * K + scol;
  const u16* gb = Bt + (size_t)(bn + srow) * K + scol;
  f32x4 acc[4][4] = {};
  const int aoff = (wr * 64 + l15) * BK + lhi * 8;
  const int boff = (wc * 64 + l15) * BK + lhi * 8;
  for (int k0 = 0; k0 < K; k0 += BK) {
    __syncthreads();
    __builtin_amdgcn_global_load_lds((__attribute__((address_space(1))) void*)(ga + k0),
                                     (__attribute__((address_space(3))) void*)(&As[tid * 8]), 16, 0, 0);
    __builtin_amdgcn_global_load_lds((__attribute__((address_space(1))) void*)(ga + (size_t)64 * K + k0),
                                     (__attribute__((address_space(3))) void*)(&As[2048 + tid * 8]), 16, 0, 0);
    __builtin_amdgcn_global_load_lds((__attribute__((address_space(1))) void*)(gb + k0),
                                     (__attribute__((address_space(3))) void*)(&Bs[tid * 8]), 16, 0, 0);
    __builtin_amdgcn_global_load_lds((__attribute__((address_space(1))) void*)(gb + (size_t)64 * K + k0),
                                     (__attribute__((address_space(3))) void*)(&Bs[2048 + tid * 8]), 16, 0, 0);
    __syncthreads();
    bf16x8 af[4], bfr[4];
#pragma unroll
    for (int i = 0; i < 4; i++) af[i] = *(const bf16x8*)&As[aoff + i * 16 * BK];
#pragma unroll
    for (int j = 0; j < 4; j++) bfr[j] = *(const bf16x8*)&Bs[boff + j * 16 * BK];
#pragma unroll
    for (int i = 0; i < 4; i++)
#pragma unroll
      for (int j = 0; j < 4; j++)
        acc[i][j] = __builtin_amdgcn_mfma_f32_16x16x32_bf16(af[i], bfr[j], acc[i][j], 0, 0, 0);
  }
  // ---- fused epilogue ----
  const int crow0 = bm + wr * 64 + lhi * 4;
  const int bsel = (blockIdx.x >= 16) ? 1 : 0;
  const int hg = (bn >> 6) + wc;  // global col>>6 for this lane's 64-col band
  if (blockIdx.y >= 10) {
    // ---- V: write transposed [b][g][64][2048], pack 4 t's per store ----
    u16* dst = vT_ + ((size_t)(bsel * KV_C + (hg - 20)) * 64) * T_C;
#pragma unroll
    for (int j = 0; j < 4; j++) {
      const int d = l15 + j * 16;
#pragma unroll
      for (int i = 0; i < 4; i++) {
        const int t2 = (crow0 + i * 16) & 2047;
        u16x4 pk;
#pragma unroll
        for (int r = 0; r < 4; r++) pk[r] = f2bf(acc[i][j][r]);
        *(u16x4*)&dst[(size_t)d * T_C + t2] = pk;
      }
    }
  } else {
    // ---- Q or K: RoPE via lane-pair shfl + table ----
    const bool isq = (blockIdx.y < 8);
    u16* dst = isq ? (qb_ + ((size_t)(bsel * H_C + hg) * T_C) * 64)
                   : (kb_ + ((size_t)(bsel * KV_C + (hg - 16)) * T_C) * 64);
    const float sc = isq ? (0.125f * 1.4426950408889634f) : 1.0f;
    const int par = l15 & 1;
#pragma unroll
    for (int j = 0; j < 4; j++) {
      const int d = l15 + j * 16;
      const int ir = (l15 >> 1) + j * 8;
#pragma unroll
      for (int i = 0; i < 4; i++)
#pragma unroll
        for (int r = 0; r < 4; r++) {
          const int t2 = (crow0 + i * 16 + r) & 2047;
          float v = acc[i][j][r];
          float p = __shfl_xor(v, 1, 64);
          f32x2 cs = tab[t2 * 32 + ir];
          float sgn = par ? cs.y : -cs.y;  // even: v*c - p*s ; odd: v*c + p*s
          dst[(size_t)t2 * 64 + d] = f2bf((v * cs.x + p * sgn) * sc);
        }
    }
  }
}

// ---------- GEMM2: C[M][N] fp32 = A[M][K]bf16 * Bt[N][K]bf16^T ----------
__global__ __launch_bounds__(256, 2) void k_gemm_bt(
    const u16* __restrict__ A, const u16* __restrict__ Bt, float* __restrict__ C,
    int M, int N, int K) {
  constexpr int BK = 32;
  __shared__ u16 As[128 * BK];
  __shared__ u16 Bs[128 * BK];
  const int tid = threadIdx.x;
  const int lane = tid & 63, wid = tid >> 6;
  const int wr = wid >> 1, wc = wid & 1;
  const int l15 = lane & 15, lhi = lane >> 4;
  const int bm = blockIdx.x * 128, bn = blockIdx.y * 128;
  const int srow = tid >> 2, scol = (tid & 3) * 8;
  const u16* ga = A + (size_t)(bm + srow) * K + scol;
  const u16* gb = Bt + (size_t)(bn + srow) * K + scol;
  f32x4 acc[4][4] = {};
  const int aoff = (wr * 64 + l15) * BK + lhi * 8;
  const int boff = (wc * 64 + l15) * BK + lhi * 8;
  for (int k0 = 0; k0 < K; k0 += BK) {
    __syncthreads();
    __builtin_amdgcn_global_load_lds((__attribute__((address_space(1))) void*)(ga + k0),
                                     (__attribute__((address_space(3))) void*)(&As[tid * 8]), 16, 0, 0);
    __builtin_amdgcn_global_load_lds((__attribute__((address_space(1))) void*)(ga + (size_t)64 * K + k0),
                                     (__attribute__((address_space(3))) void*)(&As[2048 + tid * 8]), 16, 0, 0);
    __builtin_amdgcn_global_load_lds((__attribute__((address_space(1))) void*)(gb + k0),
                                     (__attribute__((address_space(3))) void*)(&Bs[tid * 8]), 16, 0, 0);
    __builtin_amdgcn_global_load_lds((__attribute__((address_space(1))) void*)(gb + (size_t)64 * K + k0),
                                     (__attribute__((address_space(3))) void*)(&Bs[2048 + tid * 8]), 16, 0, 0);
    __syncthreads();
    bf16x8 af[4], bfr[4];
#pragma unroll
    for (int i = 0; i < 4; i++) af[i] = *(const bf16x8*)&As[aoff + i * 16 * BK];
#pragma unroll
    for (int j = 0; j < 4; j++) bfr[j] = *(const bf16x8*)&Bs[boff + j * 16 * BK];
#pragma unroll
    for (int i = 0; i < 4; i++)
#pragma unroll
      for (int j = 0; j < 4; j++)
        acc[i][j] = __builtin_amdgcn_mfma_f32_16x16x32_bf16(af[i], bfr[j], acc[i][j], 0, 0, 0);
  }
  const int crow0 = bm + wr * 64 + lhi * 4, ccol0 = bn + wc * 64 + l15;
#pragma unroll
  for (int i = 0; i < 4; i++)
#pragma unroll
    for (int j = 0; j < 4; j++)
#pragma unroll
      for (int r = 0; r < 4; r++)
        C[(size_t)(crow0 + i * 16 + r) * N + ccol0 + j * 16] = acc[i][j][r];
}

// ---------- causal flash attention v4 ----------
// v3 structure + per-lane deferred lsum (epilogue reduce) + exact skip-rescale.
__global__ __launch_bounds__(256, 4) void k_attn(
    const u16* __restrict__ q_bf, const u16* __restrict__ k_bf,
    const u16* __restrict__ vT_bf, u16* __restrict__ att_bf) {
  __shared__ __align__(16) char lds[40960];
  const int bid = blockIdx.x;
  const int g = bid >> 5, g0 = g & 7, gs = g >> 3;
  const int qb = (gs == 0) ? (31 - g0) : (gs == 1) ? g0 : (gs == 2) ? (23 - g0) : (8 + g0);
  const int hb = bid & 31;
  const int h = hb & 15, b = hb >> 4;
  const int kvh = h >> 2;
  const int tid = threadIdx.x, lane = tid & 63, w = tid >> 6;
  const int l15 = lane & 15, lhi = lane >> 4;
  const u16* Qg = q_bf + ((size_t)((b * H_C + h) * T_C) + qb * 64) * 64;
  const u16* Kg = k_bf + ((size_t)((b * KV_C + kvh) * T_C)) * 64;
  const u16* Vg = vT_bf + (size_t)(b * KV_C + kvh) * 64 * T_C;  // [64][T]

  bf16x8 qf[2];
  const int qrow = w * 16 + l15;
#pragma unroll
  for (int kc = 0; kc < 2; kc++)
    qf[kc] = *(const bf16x8*)&Qg[(size_t)qrow * 64 + kc * 32 + lhi * 8];

  f32x4 o[4] = {};
  float m[4], lsum[4];
#pragma unroll
  for (int r = 0; r < 4; r++) { m[r] = -1e30f; lsum[r] = 0.f; }

  const int nt = qb + 1;
  const int r0 = tid >> 3, j0 = tid & 7;
  const int r1 = r0 + 32;
  const int wb0 = r0 * 128 + ((j0 * 16) ^ ((r0 & 7) << 4));
  const int wb1 = r1 * 128 + ((j0 * 16) ^ ((r1 & 7) << 4));
  char* psb = lds + 0x8000 + w * 0x800;

  bf16x8 kr0, kr1, vr0, vr1;
  kr0 = *(const bf16x8*)&Kg[(size_t)r0 * 64 + j0 * 8];
  kr1 = *(const bf16x8*)&Kg[(size_t)r1 * 64 + j0 * 8];
  vr0 = *(const bf16x8*)&Vg[(size_t)r0 * T_C + j0 * 8];
  vr1 = *(const bf16x8*)&Vg[(size_t)r1 * T_C + j0 * 8];
  *(bf16x8*)(lds + wb0) = kr0;
  *(bf16x8*)(lds + wb1) = kr1;
  *(bf16x8*)(lds + 0x4000 + wb0) = vr0;
  *(bf16x8*)(lds + 0x4000 + wb1) = vr1;
  __syncthreads();

  for (int it = 0; it < nt; ++it) {
    const int t0 = it * 64;
    const int coff = (it & 1) * 0x2000;
    if (it + 1 < nt) {
      const int t1 = t0 + 64;
      kr0 = *(const bf16x8*)&Kg[(size_t)(t1 + r0) * 64 + j0 * 8];
      kr1 = *(const bf16x8*)&Kg[(size_t)(t1 + r1) * 64 + j0 * 8];
      vr0 = *(const bf16x8*)&Vg[(size_t)r0 * T_C + t1 + j0 * 8];
      vr1 = *(const bf16x8*)&Vg[(size_t)r1 * T_C + t1 + j0 * 8];
    }
    // ---- S = Q K^T ----
    bf16x8 kf[4][2];
#pragma unroll
    for (int nf = 0; nf < 4; nf++)
#pragma unroll
      for (int kc = 0; kc < 2; kc++) {
        const int row = nf * 16 + l15;
        kf[nf][kc] = *(const bf16x8*)(lds + coff + row * 128 +
                                      ((kc * 64 + lhi * 16) ^ ((l15 & 7) << 4)));
      }
    f32x4 s[4] = {};
    __builtin_amdgcn_s_setprio(1);
#pragma unroll
    for (int nf = 0; nf < 4; nf++)
#pragma unroll
      for (int kc = 0; kc < 2; kc++)
        s[nf] = __builtin_amdgcn_mfma_f32_16x16x32_bf16(qf[kc], kf[nf][kc], s[nf], 0, 0, 0);
    __builtin_amdgcn_s_setprio(0);
    // ---- causal mask on diagonal tile ----
    if (it == nt - 1) {
      const int qg = qb * 64 + w * 16 + lhi * 4;
#pragma unroll
      for (int nf = 0; nf < 4; nf++) {
        const int key = t0 + nf * 16 + l15;
#pragma unroll
        for (int r = 0; r < 4; r++)
          if (key > qg + r) s[nf][r] = -1e30f;
      }
    }
    // ---- online softmax: row max (16-lane tree), exact skip-rescale ----
    float tmax[4];
#pragma unroll
    for (int r = 0; r < 4; r++)
      tmax[r] = fmaxf(fmaxf(s[0][r], s[1][r]), fmaxf(s[2][r], s[3][r]));
#pragma unroll
    for (int x = 1; x < 16; x <<= 1)
#pragma unroll
      for (int r = 0; r < 4; r++) tmax[r] = fmaxf(tmax[r], __shfl_xor(tmax[r], x, 64));
    bool upd = (tmax[0] > m[0]) || (tmax[1] > m[1]) || (tmax[2] > m[2]) || (tmax[3] > m[3]);
    if (upd) {  // group-uniform branch; exact (skip only when max unchanged)
      float alpha[4];
#pragma unroll
      for (int r = 0; r < 4; r++) {
        float mn = fmaxf(m[r], tmax[r]);
        alpha[r] = __builtin_exp2f(m[r] - mn);
        m[r] = mn;
        lsum[r] *= alpha[r];
      }
#pragma unroll
      for (int nf = 0; nf < 4; nf++)
#pragma unroll
        for (int r = 0; r < 4; r++) o[nf][r] *= alpha[r];
    }
    // ---- P = exp2(S - m); per-lane partial lsum (reduce deferred) ----
#pragma unroll
    for (int nf = 0; nf < 4; nf++)
#pragma unroll
      for (int r = 0; r < 4; r++) {
        float p = __builtin_exp2f(s[nf][r] - m[r]);
        s[nf][r] = p;
        lsum[r] += p;
      }
    // ---- P -> per-wave LDS (swizzled) ----
#pragma unroll
    for (int nf = 0; nf < 4; nf++)
#pragma unroll
      for (int r = 0; r < 4; r++) {
        const int q_ = lhi * 4 + r;
        *(u16*)(psb + q_ * 128 + ((nf * 32 + l15 * 2) ^ ((q_ & 7) << 4))) = f2bf(s[nf][r]);
      }
    asm volatile("s_waitcnt lgkmcnt(0)" ::: "memory");
    __builtin_amdgcn_sched_barrier(0);
    // ---- O += P V ----
    __builtin_amdgcn_s_setprio(1);
#pragma unroll
    for (int kc = 0; kc < 2; kc++) {
      bf16x8 pa = *(const bf16x8*)(psb + l15 * 128 +
                                   ((kc * 64 + lhi * 16) ^ ((l15 & 7) << 4)));
#pragma unroll
      for (int nf = 0; nf < 4; nf++) {
        bf16x8 vf = *(const bf16x8*)(lds + 0x4000 + coff + (nf * 16 + l15) * 128 +
                                     ((kc * 64 + lhi * 16) ^ ((l15 & 7) << 4)));
        o[nf] = __builtin_amdgcn_mfma_f32_16x16x32_bf16(pa, vf, o[nf], 0, 0, 0);
      }
    }
    __builtin_amdgcn_s_setprio(0);
    if (it + 1 < nt) {
      const int noff = ((it + 1) & 1) * 0x2000;
      *(bf16x8*)(lds + noff + wb0) = kr0;
      *(bf16x8*)(lds + noff + wb1) = kr1;
      *(bf16x8*)(lds + 0x4000 + noff + wb0) = vr0;
      *(bf16x8*)(lds + 0x4000 + noff + wb1) = vr1;
    }
    __syncthreads();
  }
  // ---- epilogue: single lsum reduce, then O/l ----
#pragma unroll
  for (int x = 1; x < 16; x <<= 1)
#pragma unroll
    for (int r = 0; r < 4; r++) lsum[r] += __shfl_xor(lsum[r], x, 64);
  float inv[4];
#pragma unroll
  for (int r = 0; r < 4; r++) inv[r] = 1.0f / lsum[r];
  const int trow = qb * 64 + w * 16 + lhi * 4;
  const size_t obase = ((size_t)(b * T_C) + trow) * 1024 + h * 64;
#pragma unroll
  for (int nf = 0; nf < 4; nf++)
#pragma unroll
    for (int r = 0; r < 4; r++)
      att_bf[obase + (size_t)r * 1024 + nf * 16 + l15] = f2bf(o[nf][r] * inv[r]);
}

extern "C" void kernel_launch(void* const* d_in, const int* in_sizes, int n_in,
                              void* d_out, int out_size, void* d_ws, size_t ws_size,
                              hipStream_t stream) {
  const float* x  = (const float*)d_in[0];
  const float* wq = (const float*)d_in[2];
  const float* wk = (const float*)d_in[3];
  const float* wv = (const float*)d_in[4];
  const float* wo = (const float*)d_in[5];
  float* out = (float*)d_out;

  char* ws = (char*)d_ws;
  u16*   xb    = (u16*)(ws);                          //  8 MiB
  u16*   wqkvT = (u16*)(ws + (8ull  << 20));          //  3 MiB
  u16*   woT   = (u16*)(ws + (11ull << 20));          //  2 MiB
  u16*   vT_bf = (u16*)(ws + (13ull << 20));          //  2 MiB
  f32x2* tab   = (f32x2*)(ws + (15ull << 20));        // 512 KiB
  u16*   q_bf  = (u16*)(ws + (37ull << 20));          //  8 MiB
  u16*   k_bf  = (u16*)(ws + (45ull << 20));          //  2 MiB
  u16*   attb  = (u16*)(ws + (49ull << 20));          //  8 MiB

  k_cvt<<<4096, 256, 0, stream>>>(x, xb, 4096 * 1024 / 4);
  k_tr<<<dim3(32, 32), 256, 0, stream>>>(wq, wqkvT, 1024, 1024);
  k_tr<<<dim3(32, 8),  256, 0, stream>>>(wk, wqkvT + 1024 * 1024, 1024, 256);
  k_tr<<<dim3(32, 8),  256, 0, stream>>>(wv, wqkvT + 1280 * 1024, 1024, 256);
  k_tr<<<dim3(32, 32), 256, 0, stream>>>(wo, woT, 1024, 1024);
  k_costab<<<256, 256, 0, stream>>>(tab);
  k_gemm_qkv<<<dim3(32, 12), 256, 0, stream>>>(xb, wqkvT, tab, q_bf, k_bf, vT_bf);
  k_attn<<<1024, 256, 0, stream>>>(q_bf, k_bf, vT_bf, attb);
  k_gemm_bt<<<dim3(32, 8), 256, 0, stream>>>(attb, woT, out, 4096, 1024, 1024);
}

// Round 9
// 115.746 us; speedup vs baseline: 2.2041x; 1.1364x over previous
//
#include <hip/hip_runtime.h>
#include <cstdint>

typedef unsigned short u16;
typedef __attribute__((ext_vector_type(2))) float f32x2;
typedef __attribute__((ext_vector_type(4))) float f32x4;
typedef __attribute__((ext_vector_type(8))) short bf16x8;
typedef __attribute__((ext_vector_type(4))) u16 u16x4;

#define B_C 2
#define T_C 2048
#define H_C 16
#define KV_C 4

__device__ __forceinline__ u16 f2bf(float f) {
  unsigned u = __builtin_bit_cast(unsigned, f);
  u = (u + 0x7fffu + ((u >> 16) & 1u)) >> 16;
  return (u16)u;
}

__device__ __forceinline__ unsigned cvtpk(float a, float b) {
  unsigned r;
  asm("v_cvt_pk_bf16_f32 %0, %1, %2" : "=v"(r) : "v"(a), "v"(b));
  return r;
}

// ---------- x: fp32 -> bf16 ----------
__global__ void k_cvt(const float* __restrict__ in, u16* __restrict__ out, int n4) {
  int i = blockIdx.x * blockDim.x + threadIdx.x;
  if (i >= n4) return;
  f32x4 v = *(const f32x4*)(in + (size_t)i * 4);
  u16x4 o;
  o[0] = f2bf(v[0]); o[1] = f2bf(v[1]); o[2] = f2bf(v[2]); o[3] = f2bf(v[3]);
  *(u16x4*)(out + (size_t)i * 4) = o;
}

// ---------- transpose fp32 [K][N] -> bf16 [N][K] ----------
__global__ void k_tr(const float* __restrict__ in, u16* __restrict__ out, int K, int N) {
  __shared__ float t[32][33];
  int kb = blockIdx.x * 32, nb = blockIdx.y * 32;
  int tx = threadIdx.x & 31, ty = threadIdx.x >> 5;
#pragma unroll
  for (int i = 0; i < 32; i += 8) t[ty + i][tx] = in[(size_t)(kb + ty + i) * N + nb + tx];
  __syncthreads();
#pragma unroll
  for (int i = 0; i < 32; i += 8) out[(size_t)(nb + ty + i) * K + kb + tx] = f2bf(t[tx][ty + i]);
}

// ---------- RoPE cos/sin table [2048][32] ----------
__global__ void k_costab(f32x2* __restrict__ tab) {
  int idx = blockIdx.x * 256 + threadIdx.x;  // t*32 + i
  int i = idx & 31, t = idx >> 5;
  float ang = (float)t * exp2f(-(float)(2 * i) * (13.28771237954945f / 64.0f));
  float sn, cs; sincosf(ang, &sn, &cs);
  f32x2 v; v.x = cs; v.y = sn;
  tab[idx] = v;
}

// ---------- GEMM1: x @ wqkvT with fused RoPE + relayout epilogue ----------
__global__ __launch_bounds__(256, 2) void k_gemm_qkv(
    const u16* __restrict__ A, const u16* __restrict__ Bt,
    const f32x2* __restrict__ tab,
    u16* __restrict__ qb_, u16* __restrict__ kb_, u16* __restrict__ vT_) {
  constexpr int BK = 32, K = 1024;
  __shared__ u16 As[128 * BK];
  __shared__ u16 Bs[128 * BK];
  const int tid = threadIdx.x;
  const int lane = tid & 63, wid = tid >> 6;
  const int wr = wid >> 1, wc = wid & 1;
  const int l15 = lane & 15, lhi = lane >> 4;
  const int bm = blockIdx.x * 128, bn = blockIdx.y * 128;
  const int srow = tid >> 2, scol = (tid & 3) * 8;
  const u16* ga = A + (size_t)(bm + srow) * K + scol;
  const u16* gb = Bt + (size_t)(bn + srow) * K + scol;
  f32x4 acc[4][4] = {};
  const int aoff = (wr * 64 + l15) * BK + lhi * 8;
  const int boff = (wc * 64 + l15) * BK + lhi * 8;
  for (int k0 = 0; k0 < K; k0 += BK) {
    __syncthreads();
    __builtin_amdgcn_global_load_lds((__attribute__((address_space(1))) void*)(ga + k0),
                                     (__attribute__((address_space(3))) void*)(&As[tid * 8]), 16, 0, 0);
    __builtin_amdgcn_global_load_lds((__attribute__((address_space(1))) void*)(ga + (size_t)64 * K + k0),
                                     (__attribute__((address_space(3))) void*)(&As[2048 + tid * 8]), 16, 0, 0);
    __builtin_amdgcn_global_load_lds((__attribute__((address_space(1))) void*)(gb + k0),
                                     (__attribute__((address_space(3))) void*)(&Bs[tid * 8]), 16, 0, 0);
    __builtin_amdgcn_global_load_lds((__attribute__((address_space(1))) void*)(gb + (size_t)64 * K + k0),
                                     (__attribute__((address_space(3))) void*)(&Bs[2048 + tid * 8]), 16, 0, 0);
    __syncthreads();
    bf16x8 af[4], bfr[4];
#pragma unroll
    for (int i = 0; i < 4; i++) af[i] = *(const bf16x8*)&As[aoff + i * 16 * BK];
#pragma unroll
    for (int j = 0; j < 4; j++) bfr[j] = *(const bf16x8*)&Bs[boff + j * 16 * BK];
#pragma unroll
    for (int i = 0; i < 4; i++)
#pragma unroll
      for (int j = 0; j < 4; j++)
        acc[i][j] = __builtin_amdgcn_mfma_f32_16x16x32_bf16(af[i], bfr[j], acc[i][j], 0, 0, 0);
  }
  // ---- fused epilogue ----
  const int crow0 = bm + wr * 64 + lhi * 4;
  const int bsel = (blockIdx.x >= 16) ? 1 : 0;
  const int hg = (bn >> 6) + wc;
  if (blockIdx.y >= 10) {
    u16* dst = vT_ + ((size_t)(bsel * KV_C + (hg - 20)) * 64) * T_C;
#pragma unroll
    for (int j = 0; j < 4; j++) {
      const int d = l15 + j * 16;
#pragma unroll
      for (int i = 0; i < 4; i++) {
        const int t2 = (crow0 + i * 16) & 2047;
        u16x4 pk;
#pragma unroll
        for (int r = 0; r < 4; r++) pk[r] = f2bf(acc[i][j][r]);
        *(u16x4*)&dst[(size_t)d * T_C + t2] = pk;
      }
    }
  } else {
    const bool isq = (blockIdx.y < 8);
    u16* dst = isq ? (qb_ + ((size_t)(bsel * H_C + hg) * T_C) * 64)
                   : (kb_ + ((size_t)(bsel * KV_C + (hg - 16)) * T_C) * 64);
    const float sc = isq ? (0.125f * 1.4426950408889634f) : 1.0f;
    const int par = l15 & 1;
#pragma unroll
    for (int j = 0; j < 4; j++) {
      const int d = l15 + j * 16;
      const int ir = (l15 >> 1) + j * 8;
#pragma unroll
      for (int i = 0; i < 4; i++)
#pragma unroll
        for (int r = 0; r < 4; r++) {
          const int t2 = (crow0 + i * 16 + r) & 2047;
          float v = acc[i][j][r];
          float p = __shfl_xor(v, 1, 64);
          f32x2 cs = tab[t2 * 32 + ir];
          float sgn = par ? cs.y : -cs.y;
          dst[(size_t)t2 * 64 + d] = f2bf((v * cs.x + p * sgn) * sc);
        }
    }
  }
}

// ---------- GEMM2: C[M][N] fp32 = A[M][K]bf16 * Bt[N][K]bf16^T ----------
__global__ __launch_bounds__(256, 2) void k_gemm_bt(
    const u16* __restrict__ A, const u16* __restrict__ Bt, float* __restrict__ C,
    int M, int N, int K) {
  constexpr int BK = 32;
  __shared__ u16 As[128 * BK];
  __shared__ u16 Bs[128 * BK];
  const int tid = threadIdx.x;
  const int lane = tid & 63, wid = tid >> 6;
  const int wr = wid >> 1, wc = wid & 1;
  const int l15 = lane & 15, lhi = lane >> 4;
  const int bm = blockIdx.x * 128, bn = blockIdx.y * 128;
  const int srow = tid >> 2, scol = (tid & 3) * 8;
  const u16* ga = A + (size_t)(bm + srow) * K + scol;
  const u16* gb = Bt + (size_t)(bn + srow) * K + scol;
  f32x4 acc[4][4] = {};
  const int aoff = (wr * 64 + l15) * BK + lhi * 8;
  const int boff = (wc * 64 + l15) * BK + lhi * 8;
  for (int k0 = 0; k0 < K; k0 += BK) {
    __syncthreads();
    __builtin_amdgcn_global_load_lds((__attribute__((address_space(1))) void*)(ga + k0),
                                     (__attribute__((address_space(3))) void*)(&As[tid * 8]), 16, 0, 0);
    __builtin_amdgcn_global_load_lds((__attribute__((address_space(1))) void*)(ga + (size_t)64 * K + k0),
                                     (__attribute__((address_space(3))) void*)(&As[2048 + tid * 8]), 16, 0, 0);
    __builtin_amdgcn_global_load_lds((__attribute__((address_space(1))) void*)(gb + k0),
                                     (__attribute__((address_space(3))) void*)(&Bs[tid * 8]), 16, 0, 0);
    __builtin_amdgcn_global_load_lds((__attribute__((address_space(1))) void*)(gb + (size_t)64 * K + k0),
                                     (__attribute__((address_space(3))) void*)(&Bs[2048 + tid * 8]), 16, 0, 0);
    __syncthreads();
    bf16x8 af[4], bfr[4];
#pragma unroll
    for (int i = 0; i < 4; i++) af[i] = *(const bf16x8*)&As[aoff + i * 16 * BK];
#pragma unroll
    for (int j = 0; j < 4; j++) bfr[j] = *(const bf16x8*)&Bs[boff + j * 16 * BK];
#pragma unroll
    for (int i = 0; i < 4; i++)
#pragma unroll
      for (int j = 0; j < 4; j++)
        acc[i][j] = __builtin_amdgcn_mfma_f32_16x16x32_bf16(af[i], bfr[j], acc[i][j], 0, 0, 0);
  }
  const int crow0 = bm + wr * 64 + lhi * 4, ccol0 = bn + wc * 64 + l15;
#pragma unroll
  for (int i = 0; i < 4; i++)
#pragma unroll
    for (int j = 0; j < 4; j++)
#pragma unroll
      for (int r = 0; r < 4; r++)
        C[(size_t)(crow0 + i * 16 + r) * N + ccol0 + j * 16] = acc[i][j][r];
}

// ---------- causal flash attention v5 ----------
// v4 + swapped QK^T (T12): S^T = mfma(K,Q) puts q = lane&15 -> scalar m/lsum,
// 2-shfl row reduce, cvt_pk P-pack, 8x ds_write_b32. PV/staging unchanged.
__global__ __launch_bounds__(256, 4) void k_attn(
    const u16* __restrict__ q_bf, const u16* __restrict__ k_bf,
    const u16* __restrict__ vT_bf, u16* __restrict__ att_bf) {
  __shared__ __align__(16) char lds[40960];
  const int bid = blockIdx.x;
  const int g = bid >> 5, g0 = g & 7, gs = g >> 3;
  const int qb = (gs == 0) ? (31 - g0) : (gs == 1) ? g0 : (gs == 2) ? (23 - g0) : (8 + g0);
  const int hb = bid & 31;
  const int h = hb & 15, b = hb >> 4;
  const int kvh = h >> 2;
  const int tid = threadIdx.x, lane = tid & 63, w = tid >> 6;
  const int l15 = lane & 15, lhi = lane >> 4;
  const u16* Qg = q_bf + ((size_t)((b * H_C + h) * T_C) + qb * 64) * 64;
  const u16* Kg = k_bf + ((size_t)((b * KV_C + kvh) * T_C)) * 64;
  const u16* Vg = vT_bf + (size_t)(b * KV_C + kvh) * 64 * T_C;  // [64][T]

  bf16x8 qf[2];
  const int qrow = w * 16 + l15;
#pragma unroll
  for (int kc = 0; kc < 2; kc++)
    qf[kc] = *(const bf16x8*)&Qg[(size_t)qrow * 64 + kc * 32 + lhi * 8];

  f32x4 o[4] = {};
  float m = -1e30f, lsum = 0.f;

  const int nt = qb + 1;
  const int r0 = tid >> 3, j0 = tid & 7;
  const int r1 = r0 + 32;
  const int wb0 = r0 * 128 + ((j0 * 16) ^ ((r0 & 7) << 4));
  const int wb1 = r1 * 128 + ((j0 * 16) ^ ((r1 & 7) << 4));
  char* psb = lds + 0x8000 + w * 0x800;
  const int psw = (l15 & 7) << 4;

  bf16x8 kr0, kr1, vr0, vr1;
  kr0 = *(const bf16x8*)&Kg[(size_t)r0 * 64 + j0 * 8];
  kr1 = *(const bf16x8*)&Kg[(size_t)r1 * 64 + j0 * 8];
  vr0 = *(const bf16x8*)&Vg[(size_t)r0 * T_C + j0 * 8];
  vr1 = *(const bf16x8*)&Vg[(size_t)r1 * T_C + j0 * 8];
  *(bf16x8*)(lds + wb0) = kr0;
  *(bf16x8*)(lds + wb1) = kr1;
  *(bf16x8*)(lds + 0x4000 + wb0) = vr0;
  *(bf16x8*)(lds + 0x4000 + wb1) = vr1;
  __syncthreads();

  for (int it = 0; it < nt; ++it) {
    const int t0 = it * 64;
    const int coff = (it & 1) * 0x2000;
    if (it + 1 < nt) {
      const int t1 = t0 + 64;
      kr0 = *(const bf16x8*)&Kg[(size_t)(t1 + r0) * 64 + j0 * 8];
      kr1 = *(const bf16x8*)&Kg[(size_t)(t1 + r1) * 64 + j0 * 8];
      vr0 = *(const bf16x8*)&Vg[(size_t)r0 * T_C + t1 + j0 * 8];
      vr1 = *(const bf16x8*)&Vg[(size_t)r1 * T_C + t1 + j0 * 8];
    }
    // ---- S^T = K Q^T (swapped operands; q = l15, key = nf*16+lhi*4+r) ----
    bf16x8 kf[4][2];
#pragma unroll
    for (int nf = 0; nf < 4; nf++)
#pragma unroll
      for (int kc = 0; kc < 2; kc++) {
        const int row = nf * 16 + l15;
        kf[nf][kc] = *(const bf16x8*)(lds + coff + row * 128 +
                                      ((kc * 64 + lhi * 16) ^ ((l15 & 7) << 4)));
      }
    f32x4 s[4] = {};
    __builtin_amdgcn_s_setprio(1);
#pragma unroll
    for (int nf = 0; nf < 4; nf++)
#pragma unroll
      for (int kc = 0; kc < 2; kc++)
        s[nf] = __builtin_amdgcn_mfma_f32_16x16x32_bf16(kf[nf][kc], qf[kc], s[nf], 0, 0, 0);
    __builtin_amdgcn_s_setprio(0);
    // ---- causal mask on diagonal tile: key > q ----
    if (it == nt - 1) {
      const int qg = w * 16 + l15;
#pragma unroll
      for (int nf = 0; nf < 4; nf++) {
        const int kb2 = nf * 16 + lhi * 4;
#pragma unroll
        for (int r = 0; r < 4; r++)
          if (kb2 + r > qg) s[nf][r] = -1e30f;
      }
    }
    // ---- online softmax: lane owns q-row; 2-shfl reduce over lhi ----
    float a0 = fmaxf(fmaxf(s[0][0], s[0][1]), fmaxf(s[0][2], s[0][3]));
    float a1 = fmaxf(fmaxf(s[1][0], s[1][1]), fmaxf(s[1][2], s[1][3]));
    float a2 = fmaxf(fmaxf(s[2][0], s[2][1]), fmaxf(s[2][2], s[2][3]));
    float a3 = fmaxf(fmaxf(s[3][0], s[3][1]), fmaxf(s[3][2], s[3][3]));
    float tmax = fmaxf(fmaxf(a0, a1), fmaxf(a2, a3));
    tmax = fmaxf(tmax, __shfl_xor(tmax, 16, 64));
    tmax = fmaxf(tmax, __shfl_xor(tmax, 32, 64));
    if (__any(tmax > m)) {
      float mn = fmaxf(m, tmax);
      float alpha = __builtin_exp2f(m - mn);
      m = mn;
      lsum *= alpha;
      float ar[4];
#pragma unroll
      for (int r = 0; r < 4; r++) ar[r] = __shfl(alpha, lhi * 4 + r, 64);
#pragma unroll
      for (int nf = 0; nf < 4; nf++)
#pragma unroll
        for (int r = 0; r < 4; r++) o[nf][r] *= ar[r];
    }
    // ---- P = exp2(S - m), pack bf16 pairs, 8x ds_write_b32 ----
#pragma unroll
    for (int nf = 0; nf < 4; nf++) {
      float p0 = __builtin_exp2f(s[nf][0] - m);
      float p1 = __builtin_exp2f(s[nf][1] - m);
      float p2 = __builtin_exp2f(s[nf][2] - m);
      float p3 = __builtin_exp2f(s[nf][3] - m);
      lsum += (p0 + p1) + (p2 + p3);
      unsigned lo = cvtpk(p0, p1), hi = cvtpk(p2, p3);
      const int pb = ((nf * 32 + lhi * 8) ^ psw) + l15 * 128;
      *(unsigned*)(psb + pb) = lo;
      *(unsigned*)(psb + pb + 4) = hi;
    }
    asm volatile("s_waitcnt lgkmcnt(0)" ::: "memory");
    __builtin_amdgcn_sched_barrier(0);
    // ---- O += P V ----
    __builtin_amdgcn_s_setprio(1);
#pragma unroll
    for (int kc = 0; kc < 2; kc++) {
      bf16x8 pa = *(const bf16x8*)(psb + l15 * 128 +
                                   ((kc * 64 + lhi * 16) ^ ((l15 & 7) << 4)));
#pragma unroll
      for (int nf = 0; nf < 4; nf++) {
        bf16x8 vf = *(const bf16x8*)(lds + 0x4000 + coff + (nf * 16 + l15) * 128 +
                                     ((kc * 64 + lhi * 16) ^ ((l15 & 7) << 4)));
        o[nf] = __builtin_amdgcn_mfma_f32_16x16x32_bf16(pa, vf, o[nf], 0, 0, 0);
      }
    }
    __builtin_amdgcn_s_setprio(0);
    if (it + 1 < nt) {
      const int noff = ((it + 1) & 1) * 0x2000;
      *(bf16x8*)(lds + noff + wb0) = kr0;
      *(bf16x8*)(lds + noff + wb1) = kr1;
      *(bf16x8*)(lds + 0x4000 + noff + wb0) = vr0;
      *(bf16x8*)(lds + 0x4000 + noff + wb1) = vr1;
    }
    __syncthreads();
  }
  // ---- epilogue: reduce lsum over lhi, redistribute inv to O rows ----
  lsum += __shfl_xor(lsum, 16, 64);
  lsum += __shfl_xor(lsum, 32, 64);
  float inv = 1.0f / lsum;
  float invr[4];
#pragma unroll
  for (int r = 0; r < 4; r++) invr[r] = __shfl(inv, lhi * 4 + r, 64);
  const int trow = qb * 64 + w * 16 + lhi * 4;
  const size_t obase = ((size_t)(b * T_C) + trow) * 1024 + h * 64;
#pragma unroll
  for (int nf = 0; nf < 4; nf++)
#pragma unroll
    for (int r = 0; r < 4; r++)
      att_bf[obase + (size_t)r * 1024 + nf * 16 + l15] = f2bf(o[nf][r] * invr[r]);
}

extern "C" void kernel_launch(void* const* d_in, const int* in_sizes, int n_in,
                              void* d_out, int out_size, void* d_ws, size_t ws_size,
                              hipStream_t stream) {
  const float* x  = (const float*)d_in[0];
  const float* wq = (const float*)d_in[2];
  const float* wk = (const float*)d_in[3];
  const float* wv = (const float*)d_in[4];
  const float* wo = (const float*)d_in[5];
  float* out = (float*)d_out;

  char* ws = (char*)d_ws;
  u16*   xb    = (u16*)(ws);                          //  8 MiB
  u16*   wqkvT = (u16*)(ws + (8ull  << 20));          //  3 MiB
  u16*   woT   = (u16*)(ws + (11ull << 20));          //  2 MiB
  u16*   vT_bf = (u16*)(ws + (13ull << 20));          //  2 MiB
  f32x2* tab   = (f32x2*)(ws + (15ull << 20));        // 512 KiB
  u16*   q_bf  = (u16*)(ws + (37ull << 20));          //  8 MiB
  u16*   k_bf  = (u16*)(ws + (45ull << 20));          //  2 MiB
  u16*   attb  = (u16*)(ws + (49ull << 20));          //  8 MiB

  k_cvt<<<4096, 256, 0, stream>>>(x, xb, 4096 * 1024 / 4);
  k_tr<<<dim3(32, 32), 256, 0, stream>>>(wq, wqkvT, 1024, 1024);
  k_tr<<<dim3(32, 8),  256, 0, stream>>>(wk, wqkvT + 1024 * 1024, 1024, 256);
  k_tr<<<dim3(32, 8),  256, 0, stream>>>(wv, wqkvT + 1280 * 1024, 1024, 256);
  k_tr<<<dim3(32, 32), 256, 0, stream>>>(wo, woT, 1024, 1024);
  k_costab<<<256, 256, 0, stream>>>(tab);
  k_gemm_qkv<<<dim3(32, 12), 256, 0, stream>>>(xb, wqkvT, tab, q_bf, k_bf, vT_bf);
  k_attn<<<1024, 256, 0, stream>>>(q_bf, k_bf, vT_bf, attb);
  k_gemm_bt<<<dim3(32, 8), 256, 0, stream>>>(attb, woT, out, 4096, 1024, 1024);
}

// Round 10
// 114.633 us; speedup vs baseline: 2.2255x; 1.0097x over previous
//
#include <hip/hip_runtime.h>
#include <cstdint>

typedef unsigned short u16;
typedef __attribute__((ext_vector_type(2))) float f32x2;
typedef __attribute__((ext_vector_type(4))) float f32x4;
typedef __attribute__((ext_vector_type(8))) short bf16x8;
typedef __attribute__((ext_vector_type(4))) u16 u16x4;

#define B_C 2
#define T_C 2048
#define H_C 16
#define KV_C 4

__device__ __forceinline__ u16 f2bf(float f) {
  unsigned u = __builtin_bit_cast(unsigned, f);
  u = (u + 0x7fffu + ((u >> 16) & 1u)) >> 16;
  return (u16)u;
}

__device__ __forceinline__ unsigned cvtpk(float a, float b) {
  unsigned r;
  asm("v_cvt_pk_bf16_f32 %0, %1, %2" : "=v"(r) : "v"(a), "v"(b));
  return r;
}

// ---------- fused prep: x->bf16, 4 weight transposes, cos/sin table ----------
__global__ void k_prep(const float* __restrict__ x, u16* __restrict__ xb,
                       const float* __restrict__ wq, const float* __restrict__ wk,
                       const float* __restrict__ wv, const float* __restrict__ wo,
                       u16* __restrict__ wqkvT, u16* __restrict__ woT,
                       f32x2* __restrict__ tab) {
  __shared__ float t[32][33];
  const int bid = blockIdx.x, tid = threadIdx.x;
  if (bid < 4096) {
    int i = bid * 256 + tid;
    f32x4 v = *(const f32x4*)(x + (size_t)i * 4);
    u16x4 o;
    o[0] = f2bf(v[0]); o[1] = f2bf(v[1]); o[2] = f2bf(v[2]); o[3] = f2bf(v[3]);
    *(u16x4*)(xb + (size_t)i * 4) = o;
  } else if (bid < 6656) {
    const float* in; u16* out; int N, lb;
    if (bid < 5120)      { in = wq; out = wqkvT;               N = 1024; lb = bid - 4096; }
    else if (bid < 5376) { in = wk; out = wqkvT + 1024 * 1024; N = 256;  lb = bid - 5120; }
    else if (bid < 5632) { in = wv; out = wqkvT + 1280 * 1024; N = 256;  lb = bid - 5376; }
    else                 { in = wo; out = woT;                 N = 1024; lb = bid - 5632; }
    const int kb = (lb & 31) * 32, nb = (lb >> 5) * 32;
    const int tx = tid & 31, ty = tid >> 5;
#pragma unroll
    for (int i = 0; i < 32; i += 8) t[ty + i][tx] = in[(size_t)(kb + ty + i) * N + nb + tx];
    __syncthreads();
#pragma unroll
    for (int i = 0; i < 32; i += 8) out[(size_t)(nb + ty + i) * 1024 + kb + tx] = f2bf(t[tx][ty + i]);
  } else {
    int idx = (bid - 6656) * 256 + tid;  // t*32 + i
    int i = idx & 31, tt = idx >> 5;
    float ang = (float)tt * exp2f(-(float)(2 * i) * (13.28771237954945f / 64.0f));
    float sn, cs; sincosf(ang, &sn, &cs);
    f32x2 v; v.x = cs; v.y = sn;
    tab[idx] = v;
  }
}

// ---------- GEMM1: x @ wqkvT with fused RoPE + relayout epilogue ----------
__global__ __launch_bounds__(256, 2) void k_gemm_qkv(
    const u16* __restrict__ A, const u16* __restrict__ Bt,
    const f32x2* __restrict__ tab,
    u16* __restrict__ qb_, u16* __restrict__ kb_, u16* __restrict__ vT_) {
  constexpr int BK = 32, K = 1024;
  __shared__ u16 As[128 * BK];
  __shared__ u16 Bs[128 * BK];
  const int tid = threadIdx.x;
  const int lane = tid & 63, wid = tid >> 6;
  const int wr = wid >> 1, wc = wid & 1;
  const int l15 = lane & 15, lhi = lane >> 4;
  const int bm = blockIdx.x * 128, bn = blockIdx.y * 128;
  const int srow = tid >> 2, scol = (tid & 3) * 8;
  const u16* ga = A + (size_t)(bm + srow) * K + scol;
  const u16* gb = Bt + (size_t)(bn + srow) * K + scol;
  f32x4 acc[4][4] = {};
  const int aoff = (wr * 64 + l15) * BK + lhi * 8;
  const int boff = (wc * 64 + l15) * BK + lhi * 8;
  for (int k0 = 0; k0 < K; k0 += BK) {
    __syncthreads();
    __builtin_amdgcn_global_load_lds((__attribute__((address_space(1))) void*)(ga + k0),
                                     (__attribute__((address_space(3))) void*)(&As[tid * 8]), 16, 0, 0);
    __builtin_amdgcn_global_load_lds((__attribute__((address_space(1))) void*)(ga + (size_t)64 * K + k0),
                                     (__attribute__((address_space(3))) void*)(&As[2048 + tid * 8]), 16, 0, 0);
    __builtin_amdgcn_global_load_lds((__attribute__((address_space(1))) void*)(gb + k0),
                                     (__attribute__((address_space(3))) void*)(&Bs[tid * 8]), 16, 0, 0);
    __builtin_amdgcn_global_load_lds((__attribute__((address_space(1))) void*)(gb + (size_t)64 * K + k0),
                                     (__attribute__((address_space(3))) void*)(&Bs[2048 + tid * 8]), 16, 0, 0);
    __syncthreads();
    bf16x8 af[4], bfr[4];
#pragma unroll
    for (int i = 0; i < 4; i++) af[i] = *(const bf16x8*)&As[aoff + i * 16 * BK];
#pragma unroll
    for (int j = 0; j < 4; j++) bfr[j] = *(const bf16x8*)&Bs[boff + j * 16 * BK];
#pragma unroll
    for (int i = 0; i < 4; i++)
#pragma unroll
      for (int j = 0; j < 4; j++)
        acc[i][j] = __builtin_amdgcn_mfma_f32_16x16x32_bf16(af[i], bfr[j], acc[i][j], 0, 0, 0);
  }
  // ---- fused epilogue ----
  const int crow0 = bm + wr * 64 + lhi * 4;
  const int bsel = (blockIdx.x >= 16) ? 1 : 0;
  const int hg = (bn >> 6) + wc;
  if (blockIdx.y >= 10) {
    u16* dst = vT_ + ((size_t)(bsel * KV_C + (hg - 20)) * 64) * T_C;
#pragma unroll
    for (int j = 0; j < 4; j++) {
      const int d = l15 + j * 16;
#pragma unroll
      for (int i = 0; i < 4; i++) {
        const int t2 = (crow0 + i * 16) & 2047;
        u16x4 pk;
#pragma unroll
        for (int r = 0; r < 4; r++) pk[r] = f2bf(acc[i][j][r]);
        *(u16x4*)&dst[(size_t)d * T_C + t2] = pk;
      }
    }
  } else {
    const bool isq = (blockIdx.y < 8);
    u16* dst = isq ? (qb_ + ((size_t)(bsel * H_C + hg) * T_C) * 64)
                   : (kb_ + ((size_t)(bsel * KV_C + (hg - 16)) * T_C) * 64);
    const float sc = isq ? (0.125f * 1.4426950408889634f) : 1.0f;
    const int par = l15 & 1;
#pragma unroll
    for (int j = 0; j < 4; j++) {
      const int d = l15 + j * 16;
      const int ir = (l15 >> 1) + j * 8;
#pragma unroll
      for (int i = 0; i < 4; i++)
#pragma unroll
        for (int r = 0; r < 4; r++) {
          const int t2 = (crow0 + i * 16 + r) & 2047;
          float v = acc[i][j][r];
          float p = __shfl_xor(v, 1, 64);
          f32x2 cs = tab[t2 * 32 + ir];
          float sgn = par ? cs.y : -cs.y;
          dst[(size_t)t2 * 64 + d] = f2bf((v * cs.x + p * sgn) * sc);
        }
    }
  }
}

// ---------- GEMM2: C[M][N] fp32 = A[M][K]bf16 * Bt[N][K]bf16^T ----------
__global__ __launch_bounds__(256, 2) void k_gemm_bt(
    const u16* __restrict__ A, const u16* __restrict__ Bt, float* __restrict__ C,
    int M, int N, int K) {
  constexpr int BK = 32;
  __shared__ u16 As[128 * BK];
  __shared__ u16 Bs[128 * BK];
  const int tid = threadIdx.x;
  const int lane = tid & 63, wid = tid >> 6;
  const int wr = wid >> 1, wc = wid & 1;
  const int l15 = lane & 15, lhi = lane >> 4;
  const int bm = blockIdx.x * 128, bn = blockIdx.y * 128;
  const int srow = tid >> 2, scol = (tid & 3) * 8;
  const u16* ga = A + (size_t)(bm + srow) * K + scol;
  const u16* gb = Bt + (size_t)(bn + srow) * K + scol;
  f32x4 acc[4][4] = {};
  const int aoff = (wr * 64 + l15) * BK + lhi * 8;
  const int boff = (wc * 64 + l15) * BK + lhi * 8;
  for (int k0 = 0; k0 < K; k0 += BK) {
    __syncthreads();
    __builtin_amdgcn_global_load_lds((__attribute__((address_space(1))) void*)(ga + k0),
                                     (__attribute__((address_space(3))) void*)(&As[tid * 8]), 16, 0, 0);
    __builtin_amdgcn_global_load_lds((__attribute__((address_space(1))) void*)(ga + (size_t)64 * K + k0),
                                     (__attribute__((address_space(3))) void*)(&As[2048 + tid * 8]), 16, 0, 0);
    __builtin_amdgcn_global_load_lds((__attribute__((address_space(1))) void*)(gb + k0),
                                     (__attribute__((address_space(3))) void*)(&Bs[tid * 8]), 16, 0, 0);
    __builtin_amdgcn_global_load_lds((__attribute__((address_space(1))) void*)(gb + (size_t)64 * K + k0),
                                     (__attribute__((address_space(3))) void*)(&Bs[2048 + tid * 8]), 16, 0, 0);
    __syncthreads();
    bf16x8 af[4], bfr[4];
#pragma unroll
    for (int i = 0; i < 4; i++) af[i] = *(const bf16x8*)&As[aoff + i * 16 * BK];
#pragma unroll
    for (int j = 0; j < 4; j++) bfr[j] = *(const bf16x8*)&Bs[boff + j * 16 * BK];
#pragma unroll
    for (int i = 0; i < 4; i++)
#pragma unroll
      for (int j = 0; j < 4; j++)
        acc[i][j] = __builtin_amdgcn_mfma_f32_16x16x32_bf16(af[i], bfr[j], acc[i][j], 0, 0, 0);
  }
  const int crow0 = bm + wr * 64 + lhi * 4, ccol0 = bn + wc * 64 + l15;
#pragma unroll
  for (int i = 0; i < 4; i++)
#pragma unroll
    for (int j = 0; j < 4; j++)
#pragma unroll
      for (int r = 0; r < 4; r++)
        C[(size_t)(crow0 + i * 16 + r) * N + ccol0 + j * 16] = acc[i][j][r];
}

// LPT chunk table: (qb<<2)|half, half: 0=solo, 1=first, 2=second; desc length.
__device__ const unsigned char CHUNK_TAB[48] = {
    125, 126, 121, 60,  122, 117, 118, 113, 56,  114, 109, 110, 105, 52,
    106, 101, 102, 97,  48,  98,  93,  94,  89,  44,  90,  85,  86,  81,
    40,  82,  77,  78,  73,  36,  74,  69,  70,  65,  32,  66,  28,  24,
    20,  16,  12,  8,   4,   0};

// ---------- causal flash attention v6: key-split chunks + LPT ----------
// Inner loop identical to v5. Chunks <=17 key-tiles; split halves write
// unnormalized partials (O,m,l) merged by k_merge.
__global__ __launch_bounds__(256, 4) void k_attn(
    const u16* __restrict__ q_bf, const u16* __restrict__ k_bf,
    const u16* __restrict__ vT_bf, u16* __restrict__ att_bf,
    float* __restrict__ opart, float* __restrict__ lbuf, float* __restrict__ mbuf) {
  __shared__ __align__(16) char lds[40960];
  const int bid = blockIdx.x;
  const int chunk = CHUNK_TAB[bid >> 5];
  const int qb = chunk >> 2, half = chunk & 3;
  const int tA = (half == 2) ? (qb + 2) >> 1 : 0;
  const int tB = (half == 1) ? (qb + 2) >> 1 : qb + 1;
  const int hb = bid & 31;
  const int h = hb & 15, b = hb >> 4;
  const int kvh = h >> 2;
  const int tid = threadIdx.x, lane = tid & 63, w = tid >> 6;
  const int l15 = lane & 15, lhi = lane >> 4;
  const u16* Qg = q_bf + ((size_t)((b * H_C + h) * T_C) + qb * 64) * 64;
  const u16* Kg = k_bf + ((size_t)((b * KV_C + kvh) * T_C)) * 64;
  const u16* Vg = vT_bf + (size_t)(b * KV_C + kvh) * 64 * T_C;  // [64][T]

  bf16x8 qf[2];
  const int qrow = w * 16 + l15;
#pragma unroll
  for (int kc = 0; kc < 2; kc++)
    qf[kc] = *(const bf16x8*)&Qg[(size_t)qrow * 64 + kc * 32 + lhi * 8];

  f32x4 o[4] = {};
  float m = -1e30f, lsum = 0.f;

  const int r0 = tid >> 3, j0 = tid & 7;
  const int r1 = r0 + 32;
  const int wb0 = r0 * 128 + ((j0 * 16) ^ ((r0 & 7) << 4));
  const int wb1 = r1 * 128 + ((j0 * 16) ^ ((r1 & 7) << 4));
  char* psb = lds + 0x8000 + w * 0x800;
  const int psw = (l15 & 7) << 4;

  bf16x8 kr0, kr1, vr0, vr1;
  {  // prologue: tile tA
    const int tb0 = tA * 64;
    kr0 = *(const bf16x8*)&Kg[(size_t)(tb0 + r0) * 64 + j0 * 8];
    kr1 = *(const bf16x8*)&Kg[(size_t)(tb0 + r1) * 64 + j0 * 8];
    vr0 = *(const bf16x8*)&Vg[(size_t)r0 * T_C + tb0 + j0 * 8];
    vr1 = *(const bf16x8*)&Vg[(size_t)r1 * T_C + tb0 + j0 * 8];
    const int poff = (tA & 1) * 0x2000;
    *(bf16x8*)(lds + poff + wb0) = kr0;
    *(bf16x8*)(lds + poff + wb1) = kr1;
    *(bf16x8*)(lds + 0x4000 + poff + wb0) = vr0;
    *(bf16x8*)(lds + 0x4000 + poff + wb1) = vr1;
  }
  __syncthreads();

  for (int it = tA; it < tB; ++it) {
    const int t0 = it * 64;
    const int coff = (it & 1) * 0x2000;
    if (it + 1 < tB) {
      const int t1 = t0 + 64;
      kr0 = *(const bf16x8*)&Kg[(size_t)(t1 + r0) * 64 + j0 * 8];
      kr1 = *(const bf16x8*)&Kg[(size_t)(t1 + r1) * 64 + j0 * 8];
      vr0 = *(const bf16x8*)&Vg[(size_t)r0 * T_C + t1 + j0 * 8];
      vr1 = *(const bf16x8*)&Vg[(size_t)r1 * T_C + t1 + j0 * 8];
    }
    // ---- S^T = K Q^T ----
    bf16x8 kf[4][2];
#pragma unroll
    for (int nf = 0; nf < 4; nf++)
#pragma unroll
      for (int kc = 0; kc < 2; kc++) {
        const int row = nf * 16 + l15;
        kf[nf][kc] = *(const bf16x8*)(lds + coff + row * 128 +
                                      ((kc * 64 + lhi * 16) ^ ((l15 & 7) << 4)));
      }
    f32x4 s[4] = {};
    __builtin_amdgcn_s_setprio(1);
#pragma unroll
    for (int nf = 0; nf < 4; nf++)
#pragma unroll
      for (int kc = 0; kc < 2; kc++)
        s[nf] = __builtin_amdgcn_mfma_f32_16x16x32_bf16(kf[nf][kc], qf[kc], s[nf], 0, 0, 0);
    __builtin_amdgcn_s_setprio(0);
    // ---- causal mask on diagonal tile ----
    if (it == qb) {
      const int qg = w * 16 + l15;
#pragma unroll
      for (int nf = 0; nf < 4; nf++) {
        const int kb2 = nf * 16 + lhi * 4;
#pragma unroll
        for (int r = 0; r < 4; r++)
          if (kb2 + r > qg) s[nf][r] = -1e30f;
      }
    }
    // ---- online softmax ----
    float a0 = fmaxf(fmaxf(s[0][0], s[0][1]), fmaxf(s[0][2], s[0][3]));
    float a1 = fmaxf(fmaxf(s[1][0], s[1][1]), fmaxf(s[1][2], s[1][3]));
    float a2 = fmaxf(fmaxf(s[2][0], s[2][1]), fmaxf(s[2][2], s[2][3]));
    float a3 = fmaxf(fmaxf(s[3][0], s[3][1]), fmaxf(s[3][2], s[3][3]));
    float tmax = fmaxf(fmaxf(a0, a1), fmaxf(a2, a3));
    tmax = fmaxf(tmax, __shfl_xor(tmax, 16, 64));
    tmax = fmaxf(tmax, __shfl_xor(tmax, 32, 64));
    if (__any(tmax > m)) {
      float mn = fmaxf(m, tmax);
      float alpha = __builtin_exp2f(m - mn);
      m = mn;
      lsum *= alpha;
      float ar[4];
#pragma unroll
      for (int r = 0; r < 4; r++) ar[r] = __shfl(alpha, lhi * 4 + r, 64);
#pragma unroll
      for (int nf = 0; nf < 4; nf++)
#pragma unroll
        for (int r = 0; r < 4; r++) o[nf][r] *= ar[r];
    }
    // ---- P = exp2(S - m), pack, 8x ds_write_b32 ----
#pragma unroll
    for (int nf = 0; nf < 4; nf++) {
      float p0 = __builtin_exp2f(s[nf][0] - m);
      float p1 = __builtin_exp2f(s[nf][1] - m);
      float p2 = __builtin_exp2f(s[nf][2] - m);
      float p3 = __builtin_exp2f(s[nf][3] - m);
      lsum += (p0 + p1) + (p2 + p3);
      unsigned lo = cvtpk(p0, p1), hi = cvtpk(p2, p3);
      const int pb = ((nf * 32 + lhi * 8) ^ psw) + l15 * 128;
      *(unsigned*)(psb + pb) = lo;
      *(unsigned*)(psb + pb + 4) = hi;
    }
    asm volatile("s_waitcnt lgkmcnt(0)" ::: "memory");
    __builtin_amdgcn_sched_barrier(0);
    // ---- O += P V ----
    __builtin_amdgcn_s_setprio(1);
#pragma unroll
    for (int kc = 0; kc < 2; kc++) {
      bf16x8 pa = *(const bf16x8*)(psb + l15 * 128 +
                                   ((kc * 64 + lhi * 16) ^ ((l15 & 7) << 4)));
#pragma unroll
      for (int nf = 0; nf < 4; nf++) {
        bf16x8 vf = *(const bf16x8*)(lds + 0x4000 + coff + (nf * 16 + l15) * 128 +
                                     ((kc * 64 + lhi * 16) ^ ((l15 & 7) << 4)));
        o[nf] = __builtin_amdgcn_mfma_f32_16x16x32_bf16(pa, vf, o[nf], 0, 0, 0);
      }
    }
    __builtin_amdgcn_s_setprio(0);
    if (it + 1 < tB) {
      const int noff = ((it + 1) & 1) * 0x2000;
      *(bf16x8*)(lds + noff + wb0) = kr0;
      *(bf16x8*)(lds + noff + wb1) = kr1;
      *(bf16x8*)(lds + 0x4000 + noff + wb0) = vr0;
      *(bf16x8*)(lds + 0x4000 + noff + wb1) = vr1;
    }
    __syncthreads();
  }
  // ---- epilogue ----
  lsum += __shfl_xor(lsum, 16, 64);
  lsum += __shfl_xor(lsum, 32, 64);
  if (half == 0) {
    float inv = 1.0f / lsum;
    float invr[4];
#pragma unroll
    for (int r = 0; r < 4; r++) invr[r] = __shfl(inv, lhi * 4 + r, 64);
    const int trow = qb * 64 + w * 16 + lhi * 4;
    const size_t obase = ((size_t)(b * T_C) + trow) * 1024 + h * 64;
#pragma unroll
    for (int nf = 0; nf < 4; nf++)
#pragma unroll
      for (int r = 0; r < 4; r++)
        att_bf[obase + (size_t)r * 1024 + nf * 16 + l15] = f2bf(o[nf][r] * invr[r]);
  } else {
    const int slot = ((hb * 16 + (qb - 16)) << 1) + (half - 1);
    if (lhi == 0) {
      lbuf[slot * 64 + w * 16 + l15] = lsum;
      mbuf[slot * 64 + w * 16 + l15] = m;
    }
    float* od = opart + (size_t)slot * 4096 + (w * 16 + lhi * 4) * 64;
#pragma unroll
    for (int nf = 0; nf < 4; nf++)
#pragma unroll
      for (int r = 0; r < 4; r++)
        od[r * 64 + nf * 16 + l15] = o[nf][r];
  }
}

// ---------- merge split partials ----------
__global__ void k_merge(const float* __restrict__ opart, const float* __restrict__ lbuf,
                        const float* __restrict__ mbuf, u16* __restrict__ att_bf) {
  const int bid = blockIdx.x;  // hb*16 + si
  const int hb = bid >> 4, si = bid & 15;
  const int h = hb & 15, b = hb >> 4;
  const int slot0 = bid << 1, slot1 = slot0 + 1;
  const int tid = threadIdx.x;
  const int q = tid >> 2, c0 = (tid & 3) * 16;
  float l1 = lbuf[slot0 * 64 + q], m1 = mbuf[slot0 * 64 + q];
  float l2 = lbuf[slot1 * 64 + q], m2 = mbuf[slot1 * 64 + q];
  float M = fmaxf(m1, m2);
  float w1 = exp2f(m1 - M), w2 = exp2f(m2 - M);
  float inv = 1.0f / (l1 * w1 + l2 * w2);
  w1 *= inv; w2 *= inv;
  const float* o1 = opart + (size_t)slot0 * 4096 + q * 64 + c0;
  const float* o2 = opart + (size_t)slot1 * 4096 + q * 64 + c0;
  u16* dst = att_bf + ((size_t)(b * T_C + (si + 16) * 64 + q)) * 1024 + h * 64 + c0;
#pragma unroll
  for (int j = 0; j < 16; j += 4) {
    f32x4 a = *(const f32x4*)(o1 + j);
    f32x4 bb = *(const f32x4*)(o2 + j);
    u16x4 pk;
#pragma unroll
    for (int r = 0; r < 4; r++) pk[r] = f2bf(a[r] * w1 + bb[r] * w2);
    *(u16x4*)(dst + j) = pk;
  }
}

extern "C" void kernel_launch(void* const* d_in, const int* in_sizes, int n_in,
                              void* d_out, int out_size, void* d_ws, size_t ws_size,
                              hipStream_t stream) {
  const float* x  = (const float*)d_in[0];
  const float* wq = (const float*)d_in[2];
  const float* wk = (const float*)d_in[3];
  const float* wv = (const float*)d_in[4];
  const float* wo = (const float*)d_in[5];
  float* out = (float*)d_out;

  char* ws = (char*)d_ws;
  u16*   xb    = (u16*)(ws);                          //  8 MiB
  u16*   wqkvT = (u16*)(ws + (8ull  << 20));          //  3 MiB
  u16*   woT   = (u16*)(ws + (11ull << 20));          //  2 MiB
  u16*   vT_bf = (u16*)(ws + (13ull << 20));          //  2 MiB
  f32x2* tab   = (f32x2*)(ws + (15ull << 20));        // 512 KiB
  float* opart = (float*)(ws + (16ull << 20));        // 16 MiB partial O
  float* lbuf  = (float*)(ws + (33ull << 20));        // 256 KiB
  float* mbuf  = (float*)(ws + (34ull << 20));        // 256 KiB
  u16*   q_bf  = (u16*)(ws + (37ull << 20));          //  8 MiB
  u16*   k_bf  = (u16*)(ws + (45ull << 20));          //  2 MiB
  u16*   attb  = (u16*)(ws + (49ull << 20));          //  8 MiB

  k_prep<<<6912, 256, 0, stream>>>(x, xb, wq, wk, wv, wo, wqkvT, woT, tab);
  k_gemm_qkv<<<dim3(32, 12), 256, 0, stream>>>(xb, wqkvT, tab, q_bf, k_bf, vT_bf);
  k_attn<<<1536, 256, 0, stream>>>(q_bf, k_bf, vT_bf, attb, opart, lbuf, mbuf);
  k_merge<<<512, 256, 0, stream>>>(opart, lbuf, mbuf, attb);
  k_gemm_bt<<<dim3(32, 8), 256, 0, stream>>>(attb, woT, out, 4096, 1024, 1024);
}

// Round 11
// 110.392 us; speedup vs baseline: 2.3110x; 1.0384x over previous
//
#include <hip/hip_runtime.h>
#include <cstdint>

typedef unsigned short u16;
typedef __attribute__((ext_vector_type(2))) float f32x2;
typedef __attribute__((ext_vector_type(4))) float f32x4;
typedef __attribute__((ext_vector_type(8))) short bf16x8;
typedef __attribute__((ext_vector_type(4))) u16 u16x4;

#define B_C 2
#define T_C 2048
#define H_C 16
#define KV_C 4

__device__ __forceinline__ u16 f2bf(float f) {
  unsigned u = __builtin_bit_cast(unsigned, f);
  u = (u + 0x7fffu + ((u >> 16) & 1u)) >> 16;
  return (u16)u;
}

__device__ __forceinline__ unsigned cvtpk(float a, float b) {
  unsigned r;
  asm("v_cvt_pk_bf16_f32 %0, %1, %2" : "=v"(r) : "v"(a), "v"(b));
  return r;
}

#define GLL16(src, dst)                                                     \
  __builtin_amdgcn_global_load_lds(                                         \
      (__attribute__((address_space(1))) void*)(src),                       \
      (__attribute__((address_space(3))) void*)(dst), 16, 0, 0)

// ---------- fused prep: x->bf16, 4 weight transposes, cos/sin table ----------
__global__ void k_prep(const float* __restrict__ x, u16* __restrict__ xb,
                       const float* __restrict__ wq, const float* __restrict__ wk,
                       const float* __restrict__ wv, const float* __restrict__ wo,
                       u16* __restrict__ wqkvT, u16* __restrict__ woT,
                       f32x2* __restrict__ tab) {
  __shared__ float t[32][33];
  const int bid = blockIdx.x, tid = threadIdx.x;
  if (bid < 4096) {
    int i = bid * 256 + tid;
    f32x4 v = *(const f32x4*)(x + (size_t)i * 4);
    u16x4 o;
    o[0] = f2bf(v[0]); o[1] = f2bf(v[1]); o[2] = f2bf(v[2]); o[3] = f2bf(v[3]);
    *(u16x4*)(xb + (size_t)i * 4) = o;
  } else if (bid < 6656) {
    const float* in; u16* out; int N, lb;
    if (bid < 5120)      { in = wq; out = wqkvT;               N = 1024; lb = bid - 4096; }
    else if (bid < 5376) { in = wk; out = wqkvT + 1024 * 1024; N = 256;  lb = bid - 5120; }
    else if (bid < 5632) { in = wv; out = wqkvT + 1280 * 1024; N = 256;  lb = bid - 5376; }
    else                 { in = wo; out = woT;                 N = 1024; lb = bid - 5632; }
    const int kb = (lb & 31) * 32, nb = (lb >> 5) * 32;
    const int tx = tid & 31, ty = tid >> 5;
#pragma unroll
    for (int i = 0; i < 32; i += 8) t[ty + i][tx] = in[(size_t)(kb + ty + i) * N + nb + tx];
    __syncthreads();
#pragma unroll
    for (int i = 0; i < 32; i += 8) out[(size_t)(nb + ty + i) * 1024 + kb + tx] = f2bf(t[tx][ty + i]);
  } else {
    int idx = (bid - 6656) * 256 + tid;  // t*32 + i
    int i = idx & 31, tt = idx >> 5;
    float ang = (float)tt * exp2f(-(float)(2 * i) * (13.28771237954945f / 64.0f));
    float sn, cs; sincosf(ang, &sn, &cs);
    f32x2 v; v.x = cs; v.y = sn;
    tab[idx] = v;
  }
}

// ---------- GEMM1: x @ wqkvT, 2-phase pipelined, fused RoPE epilogue ----------
__global__ __launch_bounds__(256, 2) void k_gemm_qkv(
    const u16* __restrict__ A, const u16* __restrict__ Bt,
    const f32x2* __restrict__ tab,
    u16* __restrict__ qb_, u16* __restrict__ kb_, u16* __restrict__ vT_) {
  constexpr int BK = 32, K = 1024;
  __shared__ u16 As[2][128 * BK];
  __shared__ u16 Bs[2][128 * BK];
  const int tid = threadIdx.x;
  const int lane = tid & 63, wid = tid >> 6;
  const int wr = wid >> 1, wc = wid & 1;
  const int l15 = lane & 15, lhi = lane >> 4;
  const int bm = blockIdx.x * 128, bn = blockIdx.y * 128;
  const int srow = tid >> 2, scol = (tid & 3) * 8;
  const u16* ga = A + (size_t)(bm + srow) * K + scol;
  const u16* gb = Bt + (size_t)(bn + srow) * K + scol;
  f32x4 acc[4][4] = {};
  const int aoff = (wr * 64 + l15) * BK + lhi * 8;
  const int boff = (wc * 64 + l15) * BK + lhi * 8;
  // prologue: stage tile 0 -> buf 0
  GLL16(ga, &As[0][tid * 8]);
  GLL16(ga + (size_t)64 * K, &As[0][2048 + tid * 8]);
  GLL16(gb, &Bs[0][tid * 8]);
  GLL16(gb + (size_t)64 * K, &Bs[0][2048 + tid * 8]);
  __syncthreads();
  int cur = 0;
  for (int k0 = 0; k0 < K; k0 += BK) {
    if (k0 + BK < K) {  // stage next tile into other buffer (overlaps MFMA)
      const int nb2 = cur ^ 1;
      GLL16(ga + k0 + BK, &As[nb2][tid * 8]);
      GLL16(ga + (size_t)64 * K + k0 + BK, &As[nb2][2048 + tid * 8]);
      GLL16(gb + k0 + BK, &Bs[nb2][tid * 8]);
      GLL16(gb + (size_t)64 * K + k0 + BK, &Bs[nb2][2048 + tid * 8]);
    }
    bf16x8 af[4], bfr[4];
#pragma unroll
    for (int i = 0; i < 4; i++) af[i] = *(const bf16x8*)&As[cur][aoff + i * 16 * BK];
#pragma unroll
    for (int j = 0; j < 4; j++) bfr[j] = *(const bf16x8*)&Bs[cur][boff + j * 16 * BK];
#pragma unroll
    for (int i = 0; i < 4; i++)
#pragma unroll
      for (int j = 0; j < 4; j++)
        acc[i][j] = __builtin_amdgcn_mfma_f32_16x16x32_bf16(af[i], bfr[j], acc[i][j], 0, 0, 0);
    __syncthreads();
    cur ^= 1;
  }
  // ---- fused epilogue ----
  const int crow0 = bm + wr * 64 + lhi * 4;
  const int bsel = (blockIdx.x >= 16) ? 1 : 0;
  const int hg = (bn >> 6) + wc;
  if (blockIdx.y >= 10) {
    u16* dst = vT_ + ((size_t)(bsel * KV_C + (hg - 20)) * 64) * T_C;
#pragma unroll
    for (int j = 0; j < 4; j++) {
      const int d = l15 + j * 16;
#pragma unroll
      for (int i = 0; i < 4; i++) {
        const int t2 = (crow0 + i * 16) & 2047;
        u16x4 pk;
#pragma unroll
        for (int r = 0; r < 4; r++) pk[r] = f2bf(acc[i][j][r]);
        *(u16x4*)&dst[(size_t)d * T_C + t2] = pk;
      }
    }
  } else {
    const bool isq = (blockIdx.y < 8);
    u16* dst = isq ? (qb_ + ((size_t)(bsel * H_C + hg) * T_C) * 64)
                   : (kb_ + ((size_t)(bsel * KV_C + (hg - 16)) * T_C) * 64);
    const float sc = isq ? (0.125f * 1.4426950408889634f) : 1.0f;
    const int par = l15 & 1;
#pragma unroll
    for (int j = 0; j < 4; j++) {
      const int d = l15 + j * 16;
      const int ir = (l15 >> 1) + j * 8;
#pragma unroll
      for (int i = 0; i < 4; i++)
#pragma unroll
        for (int r = 0; r < 4; r++) {
          const int t2 = (crow0 + i * 16 + r) & 2047;
          float v = acc[i][j][r];
          float p = __shfl_xor(v, 1, 64);
          f32x2 cs = tab[t2 * 32 + ir];
          float sgn = par ? cs.y : -cs.y;
          dst[(size_t)t2 * 64 + d] = f2bf((v * cs.x + p * sgn) * sc);
        }
    }
  }
}

// ---------- GEMM2: C = A * Bt^T, 2-phase pipelined ----------
__global__ __launch_bounds__(256, 2) void k_gemm_bt(
    const u16* __restrict__ A, const u16* __restrict__ Bt, float* __restrict__ C,
    int M, int N, int K) {
  constexpr int BK = 32;
  __shared__ u16 As[2][128 * BK];
  __shared__ u16 Bs[2][128 * BK];
  const int tid = threadIdx.x;
  const int lane = tid & 63, wid = tid >> 6;
  const int wr = wid >> 1, wc = wid & 1;
  const int l15 = lane & 15, lhi = lane >> 4;
  const int bm = blockIdx.x * 128, bn = blockIdx.y * 128;
  const int srow = tid >> 2, scol = (tid & 3) * 8;
  const u16* ga = A + (size_t)(bm + srow) * K + scol;
  const u16* gb = Bt + (size_t)(bn + srow) * K + scol;
  f32x4 acc[4][4] = {};
  const int aoff = (wr * 64 + l15) * BK + lhi * 8;
  const int boff = (wc * 64 + l15) * BK + lhi * 8;
  GLL16(ga, &As[0][tid * 8]);
  GLL16(ga + (size_t)64 * K, &As[0][2048 + tid * 8]);
  GLL16(gb, &Bs[0][tid * 8]);
  GLL16(gb + (size_t)64 * K, &Bs[0][2048 + tid * 8]);
  __syncthreads();
  int cur = 0;
  for (int k0 = 0; k0 < K; k0 += BK) {
    if (k0 + BK < K) {
      const int nb2 = cur ^ 1;
      GLL16(ga + k0 + BK, &As[nb2][tid * 8]);
      GLL16(ga + (size_t)64 * K + k0 + BK, &As[nb2][2048 + tid * 8]);
      GLL16(gb + k0 + BK, &Bs[nb2][tid * 8]);
      GLL16(gb + (size_t)64 * K + k0 + BK, &Bs[nb2][2048 + tid * 8]);
    }
    bf16x8 af[4], bfr[4];
#pragma unroll
    for (int i = 0; i < 4; i++) af[i] = *(const bf16x8*)&As[cur][aoff + i * 16 * BK];
#pragma unroll
    for (int j = 0; j < 4; j++) bfr[j] = *(const bf16x8*)&Bs[cur][boff + j * 16 * BK];
#pragma unroll
    for (int i = 0; i < 4; i++)
#pragma unroll
      for (int j = 0; j < 4; j++)
        acc[i][j] = __builtin_amdgcn_mfma_f32_16x16x32_bf16(af[i], bfr[j], acc[i][j], 0, 0, 0);
    __syncthreads();
    cur ^= 1;
  }
  const int crow0 = bm + wr * 64 + lhi * 4, ccol0 = bn + wc * 64 + l15;
#pragma unroll
  for (int i = 0; i < 4; i++)
#pragma unroll
    for (int j = 0; j < 4; j++)
#pragma unroll
      for (int r = 0; r < 4; r++)
        C[(size_t)(crow0 + i * 16 + r) * N + ccol0 + j * 16] = acc[i][j][r];
}

// ---------- causal flash attention v5 (R9 proven: 48 us) ----------
__global__ __launch_bounds__(256, 4) void k_attn(
    const u16* __restrict__ q_bf, const u16* __restrict__ k_bf,
    const u16* __restrict__ vT_bf, u16* __restrict__ att_bf) {
  __shared__ __align__(16) char lds[40960];
  const int bid = blockIdx.x;
  const int g = bid >> 5, g0 = g & 7, gs = g >> 3;
  const int qb = (gs == 0) ? (31 - g0) : (gs == 1) ? g0 : (gs == 2) ? (23 - g0) : (8 + g0);
  const int hb = bid & 31;
  const int h = hb & 15, b = hb >> 4;
  const int kvh = h >> 2;
  const int tid = threadIdx.x, lane = tid & 63, w = tid >> 6;
  const int l15 = lane & 15, lhi = lane >> 4;
  const u16* Qg = q_bf + ((size_t)((b * H_C + h) * T_C) + qb * 64) * 64;
  const u16* Kg = k_bf + ((size_t)((b * KV_C + kvh) * T_C)) * 64;
  const u16* Vg = vT_bf + (size_t)(b * KV_C + kvh) * 64 * T_C;  // [64][T]

  bf16x8 qf[2];
  const int qrow = w * 16 + l15;
#pragma unroll
  for (int kc = 0; kc < 2; kc++)
    qf[kc] = *(const bf16x8*)&Qg[(size_t)qrow * 64 + kc * 32 + lhi * 8];

  f32x4 o[4] = {};
  float m = -1e30f, lsum = 0.f;

  const int nt = qb + 1;
  const int r0 = tid >> 3, j0 = tid & 7;
  const int r1 = r0 + 32;
  const int wb0 = r0 * 128 + ((j0 * 16) ^ ((r0 & 7) << 4));
  const int wb1 = r1 * 128 + ((j0 * 16) ^ ((r1 & 7) << 4));
  char* psb = lds + 0x8000 + w * 0x800;
  const int psw = (l15 & 7) << 4;

  bf16x8 kr0, kr1, vr0, vr1;
  kr0 = *(const bf16x8*)&Kg[(size_t)r0 * 64 + j0 * 8];
  kr1 = *(const bf16x8*)&Kg[(size_t)r1 * 64 + j0 * 8];
  vr0 = *(const bf16x8*)&Vg[(size_t)r0 * T_C + j0 * 8];
  vr1 = *(const bf16x8*)&Vg[(size_t)r1 * T_C + j0 * 8];
  *(bf16x8*)(lds + wb0) = kr0;
  *(bf16x8*)(lds + wb1) = kr1;
  *(bf16x8*)(lds + 0x4000 + wb0) = vr0;
  *(bf16x8*)(lds + 0x4000 + wb1) = vr1;
  __syncthreads();

  for (int it = 0; it < nt; ++it) {
    const int t0 = it * 64;
    const int coff = (it & 1) * 0x2000;
    if (it + 1 < nt) {
      const int t1 = t0 + 64;
      kr0 = *(const bf16x8*)&Kg[(size_t)(t1 + r0) * 64 + j0 * 8];
      kr1 = *(const bf16x8*)&Kg[(size_t)(t1 + r1) * 64 + j0 * 8];
      vr0 = *(const bf16x8*)&Vg[(size_t)r0 * T_C + t1 + j0 * 8];
      vr1 = *(const bf16x8*)&Vg[(size_t)r1 * T_C + t1 + j0 * 8];
    }
    // ---- S^T = K Q^T (swapped operands; q = l15, key = nf*16+lhi*4+r) ----
    bf16x8 kf[4][2];
#pragma unroll
    for (int nf = 0; nf < 4; nf++)
#pragma unroll
      for (int kc = 0; kc < 2; kc++) {
        const int row = nf * 16 + l15;
        kf[nf][kc] = *(const bf16x8*)(lds + coff + row * 128 +
                                      ((kc * 64 + lhi * 16) ^ ((l15 & 7) << 4)));
      }
    f32x4 s[4] = {};
    __builtin_amdgcn_s_setprio(1);
#pragma unroll
    for (int nf = 0; nf < 4; nf++)
#pragma unroll
      for (int kc = 0; kc < 2; kc++)
        s[nf] = __builtin_amdgcn_mfma_f32_16x16x32_bf16(kf[nf][kc], qf[kc], s[nf], 0, 0, 0);
    __builtin_amdgcn_s_setprio(0);
    // ---- causal mask on diagonal tile: key > q ----
    if (it == nt - 1) {
      const int qg = w * 16 + l15;
#pragma unroll
      for (int nf = 0; nf < 4; nf++) {
        const int kb2 = nf * 16 + lhi * 4;
#pragma unroll
        for (int r = 0; r < 4; r++)
          if (kb2 + r > qg) s[nf][r] = -1e30f;
      }
    }
    // ---- online softmax: lane owns q-row; 2-shfl reduce over lhi ----
    float a0 = fmaxf(fmaxf(s[0][0], s[0][1]), fmaxf(s[0][2], s[0][3]));
    float a1 = fmaxf(fmaxf(s[1][0], s[1][1]), fmaxf(s[1][2], s[1][3]));
    float a2 = fmaxf(fmaxf(s[2][0], s[2][1]), fmaxf(s[2][2], s[2][3]));
    float a3 = fmaxf(fmaxf(s[3][0], s[3][1]), fmaxf(s[3][2], s[3][3]));
    float tmax = fmaxf(fmaxf(a0, a1), fmaxf(a2, a3));
    tmax = fmaxf(tmax, __shfl_xor(tmax, 16, 64));
    tmax = fmaxf(tmax, __shfl_xor(tmax, 32, 64));
    if (__any(tmax > m)) {
      float mn = fmaxf(m, tmax);
      float alpha = __builtin_exp2f(m - mn);
      m = mn;
      lsum *= alpha;
      float ar[4];
#pragma unroll
      for (int r = 0; r < 4; r++) ar[r] = __shfl(alpha, lhi * 4 + r, 64);
#pragma unroll
      for (int nf = 0; nf < 4; nf++)
#pragma unroll
        for (int r = 0; r < 4; r++) o[nf][r] *= ar[r];
    }
    // ---- P = exp2(S - m), pack bf16 pairs, 8x ds_write_b32 ----
#pragma unroll
    for (int nf = 0; nf < 4; nf++) {
      float p0 = __builtin_exp2f(s[nf][0] - m);
      float p1 = __builtin_exp2f(s[nf][1] - m);
      float p2 = __builtin_exp2f(s[nf][2] - m);
      float p3 = __builtin_exp2f(s[nf][3] - m);
      lsum += (p0 + p1) + (p2 + p3);
      unsigned lo = cvtpk(p0, p1), hi = cvtpk(p2, p3);
      const int pb = ((nf * 32 + lhi * 8) ^ psw) + l15 * 128;
      *(unsigned*)(psb + pb) = lo;
      *(unsigned*)(psb + pb + 4) = hi;
    }
    asm volatile("s_waitcnt lgkmcnt(0)" ::: "memory");
    __builtin_amdgcn_sched_barrier(0);
    // ---- O += P V ----
    __builtin_amdgcn_s_setprio(1);
#pragma unroll
    for (int kc = 0; kc < 2; kc++) {
      bf16x8 pa = *(const bf16x8*)(psb + l15 * 128 +
                                   ((kc * 64 + lhi * 16) ^ ((l15 & 7) << 4)));
#pragma unroll
      for (int nf = 0; nf < 4; nf++) {
        bf16x8 vf = *(const bf16x8*)(lds + 0x4000 + coff + (nf * 16 + l15) * 128 +
                                     ((kc * 64 + lhi * 16) ^ ((l15 & 7) << 4)));
        o[nf] = __builtin_amdgcn_mfma_f32_16x16x32_bf16(pa, vf, o[nf], 0, 0, 0);
      }
    }
    __builtin_amdgcn_s_setprio(0);
    if (it + 1 < nt) {
      const int noff = ((it + 1) & 1) * 0x2000;
      *(bf16x8*)(lds + noff + wb0) = kr0;
      *(bf16x8*)(lds + noff + wb1) = kr1;
      *(bf16x8*)(lds + 0x4000 + noff + wb0) = vr0;
      *(bf16x8*)(lds + 0x4000 + noff + wb1) = vr1;
    }
    __syncthreads();
  }
  // ---- epilogue: reduce lsum over lhi, redistribute inv to O rows ----
  lsum += __shfl_xor(lsum, 16, 64);
  lsum += __shfl_xor(lsum, 32, 64);
  float inv = 1.0f / lsum;
  float invr[4];
#pragma unroll
  for (int r = 0; r < 4; r++) invr[r] = __shfl(inv, lhi * 4 + r, 64);
  const int trow = qb * 64 + w * 16 + lhi * 4;
  const size_t obase = ((size_t)(b * T_C) + trow) * 1024 + h * 64;
#pragma unroll
  for (int nf = 0; nf < 4; nf++)
#pragma unroll
    for (int r = 0; r < 4; r++)
      att_bf[obase + (size_t)r * 1024 + nf * 16 + l15] = f2bf(o[nf][r] * invr[r]);
}

extern "C" void kernel_launch(void* const* d_in, const int* in_sizes, int n_in,
                              void* d_out, int out_size, void* d_ws, size_t ws_size,
                              hipStream_t stream) {
  const float* x  = (const float*)d_in[0];
  const float* wq = (const float*)d_in[2];
  const float* wk = (const float*)d_in[3];
  const float* wv = (const float*)d_in[4];
  const float* wo = (const float*)d_in[5];
  float* out = (float*)d_out;

  char* ws = (char*)d_ws;
  u16*   xb    = (u16*)(ws);                          //  8 MiB
  u16*   wqkvT = (u16*)(ws + (8ull  << 20));          //  3 MiB
  u16*   woT   = (u16*)(ws + (11ull << 20));          //  2 MiB
  u16*   vT_bf = (u16*)(ws + (13ull << 20));          //  2 MiB
  f32x2* tab   = (f32x2*)(ws + (15ull << 20));        // 512 KiB
  u16*   q_bf  = (u16*)(ws + (37ull << 20));          //  8 MiB
  u16*   k_bf  = (u16*)(ws + (45ull << 20));          //  2 MiB
  u16*   attb  = (u16*)(ws + (49ull << 20));          //  8 MiB

  k_prep<<<6912, 256, 0, stream>>>(x, xb, wq, wk, wv, wo, wqkvT, woT, tab);
  k_gemm_qkv<<<dim3(32, 12), 256, 0, stream>>>(xb, wqkvT, tab, q_bf, k_bf, vT_bf);
  k_attn<<<1024, 256, 0, stream>>>(q_bf, k_bf, vT_bf, attb);
  k_gemm_bt<<<dim3(32, 8), 256, 0, stream>>>(attb, woT, out, 4096, 1024, 1024);
}

// Round 12
// 108.382 us; speedup vs baseline: 2.3538x; 1.0185x over previous
//
#include <hip/hip_runtime.h>
#include <cstdint>

typedef unsigned short u16;
typedef __attribute__((ext_vector_type(2))) float f32x2;
typedef __attribute__((ext_vector_type(4))) float f32x4;
typedef __attribute__((ext_vector_type(8))) short bf16x8;
typedef __attribute__((ext_vector_type(4))) u16 u16x4;

#define B_C 2
#define T_C 2048
#define H_C 16
#define KV_C 4

__device__ __forceinline__ u16 f2bf(float f) {
  unsigned u = __builtin_bit_cast(unsigned, f);
  u = (u + 0x7fffu + ((u >> 16) & 1u)) >> 16;
  return (u16)u;
}

__device__ __forceinline__ unsigned cvtpk(float a, float b) {
  unsigned r;
  asm("v_cvt_pk_bf16_f32 %0, %1, %2" : "=v"(r) : "v"(a), "v"(b));
  return r;
}

#define GLL16(src, dst)                                                     \
  __builtin_amdgcn_global_load_lds(                                         \
      (__attribute__((address_space(1))) void*)(src),                       \
      (__attribute__((address_space(3))) void*)(dst), 16, 0, 0)

// ---------- fused prep: x->bf16, 4 weight transposes, cos/sin table ----------
__global__ void k_prep(const float* __restrict__ x, u16* __restrict__ xb,
                       const float* __restrict__ wq, const float* __restrict__ wk,
                       const float* __restrict__ wv, const float* __restrict__ wo,
                       u16* __restrict__ wqkvT, u16* __restrict__ woT,
                       f32x2* __restrict__ tab) {
  __shared__ float t[32][33];
  const int bid = blockIdx.x, tid = threadIdx.x;
  if (bid < 4096) {
    int i = bid * 256 + tid;
    f32x4 v = *(const f32x4*)(x + (size_t)i * 4);
    u16x4 o;
    o[0] = f2bf(v[0]); o[1] = f2bf(v[1]); o[2] = f2bf(v[2]); o[3] = f2bf(v[3]);
    *(u16x4*)(xb + (size_t)i * 4) = o;
  } else if (bid < 6656) {
    const float* in; u16* out; int N, lb;
    if (bid < 5120)      { in = wq; out = wqkvT;               N = 1024; lb = bid - 4096; }
    else if (bid < 5376) { in = wk; out = wqkvT + 1024 * 1024; N = 256;  lb = bid - 5120; }
    else if (bid < 5632) { in = wv; out = wqkvT + 1280 * 1024; N = 256;  lb = bid - 5376; }
    else                 { in = wo; out = woT;                 N = 1024; lb = bid - 5632; }
    const int kb = (lb & 31) * 32, nb = (lb >> 5) * 32;
    const int tx = tid & 31, ty = tid >> 5;
#pragma unroll
    for (int i = 0; i < 32; i += 8) t[ty + i][tx] = in[(size_t)(kb + ty + i) * N + nb + tx];
    __syncthreads();
#pragma unroll
    for (int i = 0; i < 32; i += 8) out[(size_t)(nb + ty + i) * 1024 + kb + tx] = f2bf(t[tx][ty + i]);
  } else {
    int idx = (bid - 6656) * 256 + tid;  // t*32 + i
    int i = idx & 31, tt = idx >> 5;
    float ang = (float)tt * exp2f(-(float)(2 * i) * (13.28771237954945f / 64.0f));
    float sn, cs; sincosf(ang, &sn, &cs);
    f32x2 v; v.x = cs; v.y = sn;
    tab[idx] = v;
  }
}

// ---------- GEMM1: x @ wqkvT, 3-buf counted-vmcnt pipeline, RoPE epilogue ----------
__global__ __launch_bounds__(256, 2) void k_gemm_qkv(
    const u16* __restrict__ A, const u16* __restrict__ Bt,
    const f32x2* __restrict__ tab,
    u16* __restrict__ qb_, u16* __restrict__ kb_, u16* __restrict__ vT_) {
  constexpr int BK = 32, K = 1024, NT = K / BK;
  __shared__ u16 As[3][128 * BK];
  __shared__ u16 Bs[3][128 * BK];
  const int tid = threadIdx.x;
  const int lane = tid & 63, wid = tid >> 6;
  const int wr = wid >> 1, wc = wid & 1;
  const int l15 = lane & 15, lhi = lane >> 4;
  const int bm = blockIdx.x * 128, bn = blockIdx.y * 128;
  const int srow = tid >> 2, scol = (tid & 3) * 8;
  const u16* ga = A + (size_t)(bm + srow) * K + scol;
  const u16* gb = Bt + (size_t)(bn + srow) * K + scol;
  f32x4 acc[4][4] = {};
  const int aoff = (wr * 64 + l15) * BK + lhi * 8;
  const int boff = (wc * 64 + l15) * BK + lhi * 8;
  // prologue: stage tiles 0,1 -> bufs 0,1 (no wait)
#pragma unroll
  for (int p = 0; p < 2; p++) {
    GLL16(ga + p * BK, &As[p][tid * 8]);
    GLL16(ga + (size_t)64 * K + p * BK, &As[p][2048 + tid * 8]);
    GLL16(gb + p * BK, &Bs[p][tid * 8]);
    GLL16(gb + (size_t)64 * K + p * BK, &Bs[p][2048 + tid * 8]);
  }
  int cur = 0, nxt = 2;
  for (int k = 0; k < NT; ++k) {
    if (k + 1 < NT) asm volatile("s_waitcnt vmcnt(4)" ::: "memory");
    else            asm volatile("s_waitcnt vmcnt(0)" ::: "memory");
    __builtin_amdgcn_s_barrier();
    if (k + 2 < NT) {  // stage tile k+2 (flies across next barrier)
      const int k2 = (k + 2) * BK;
      GLL16(ga + k2, &As[nxt][tid * 8]);
      GLL16(ga + (size_t)64 * K + k2, &As[nxt][2048 + tid * 8]);
      GLL16(gb + k2, &Bs[nxt][tid * 8]);
      GLL16(gb + (size_t)64 * K + k2, &Bs[nxt][2048 + tid * 8]);
    }
    bf16x8 af[4], bfr[4];
#pragma unroll
    for (int i = 0; i < 4; i++) af[i] = *(const bf16x8*)&As[cur][aoff + i * 16 * BK];
#pragma unroll
    for (int j = 0; j < 4; j++) bfr[j] = *(const bf16x8*)&Bs[cur][boff + j * 16 * BK];
#pragma unroll
    for (int i = 0; i < 4; i++)
#pragma unroll
      for (int j = 0; j < 4; j++)
        acc[i][j] = __builtin_amdgcn_mfma_f32_16x16x32_bf16(af[i], bfr[j], acc[i][j], 0, 0, 0);
    cur = (cur == 2) ? 0 : cur + 1;
    nxt = (nxt == 2) ? 0 : nxt + 1;
  }
  // ---- fused epilogue ----
  const int crow0 = bm + wr * 64 + lhi * 4;
  const int bsel = (blockIdx.x >= 16) ? 1 : 0;
  const int hg = (bn >> 6) + wc;
  if (blockIdx.y >= 10) {
    u16* dst = vT_ + ((size_t)(bsel * KV_C + (hg - 20)) * 64) * T_C;
#pragma unroll
    for (int j = 0; j < 4; j++) {
      const int d = l15 + j * 16;
#pragma unroll
      for (int i = 0; i < 4; i++) {
        const int t2 = (crow0 + i * 16) & 2047;
        u16x4 pk;
#pragma unroll
        for (int r = 0; r < 4; r++) pk[r] = f2bf(acc[i][j][r]);
        *(u16x4*)&dst[(size_t)d * T_C + t2] = pk;
      }
    }
  } else {
    const bool isq = (blockIdx.y < 8);
    u16* dst = isq ? (qb_ + ((size_t)(bsel * H_C + hg) * T_C) * 64)
                   : (kb_ + ((size_t)(bsel * KV_C + (hg - 16)) * T_C) * 64);
    const float sc = isq ? (0.125f * 1.4426950408889634f) : 1.0f;
    const int par = l15 & 1;
#pragma unroll
    for (int j = 0; j < 4; j++) {
      const int d = l15 + j * 16;
      const int ir = (l15 >> 1) + j * 8;
#pragma unroll
      for (int i = 0; i < 4; i++)
#pragma unroll
        for (int r = 0; r < 4; r++) {
          const int t2 = (crow0 + i * 16 + r) & 2047;
          float v = acc[i][j][r];
          float p = __shfl_xor(v, 1, 64);
          f32x2 cs = tab[t2 * 32 + ir];
          float sgn = par ? cs.y : -cs.y;
          dst[(size_t)t2 * 64 + d] = f2bf((v * cs.x + p * sgn) * sc);
        }
    }
  }
}

// ---------- GEMM2: C = A * Bt^T, 3-buf counted-vmcnt pipeline ----------
__global__ __launch_bounds__(256, 2) void k_gemm_bt(
    const u16* __restrict__ A, const u16* __restrict__ Bt, float* __restrict__ C,
    int M, int N, int K) {
  constexpr int BK = 32;
  __shared__ u16 As[3][128 * BK];
  __shared__ u16 Bs[3][128 * BK];
  const int tid = threadIdx.x;
  const int lane = tid & 63, wid = tid >> 6;
  const int wr = wid >> 1, wc = wid & 1;
  const int l15 = lane & 15, lhi = lane >> 4;
  const int bm = blockIdx.x * 128, bn = blockIdx.y * 128;
  const int srow = tid >> 2, scol = (tid & 3) * 8;
  const u16* ga = A + (size_t)(bm + srow) * K + scol;
  const u16* gb = Bt + (size_t)(bn + srow) * K + scol;
  f32x4 acc[4][4] = {};
  const int aoff = (wr * 64 + l15) * BK + lhi * 8;
  const int boff = (wc * 64 + l15) * BK + lhi * 8;
  const int NT = K / BK;
#pragma unroll
  for (int p = 0; p < 2; p++) {
    GLL16(ga + p * BK, &As[p][tid * 8]);
    GLL16(ga + (size_t)64 * K + p * BK, &As[p][2048 + tid * 8]);
    GLL16(gb + p * BK, &Bs[p][tid * 8]);
    GLL16(gb + (size_t)64 * K + p * BK, &Bs[p][2048 + tid * 8]);
  }
  int cur = 0, nxt = 2;
  for (int k = 0; k < NT; ++k) {
    if (k + 1 < NT) asm volatile("s_waitcnt vmcnt(4)" ::: "memory");
    else            asm volatile("s_waitcnt vmcnt(0)" ::: "memory");
    __builtin_amdgcn_s_barrier();
    if (k + 2 < NT) {
      const int k2 = (k + 2) * BK;
      GLL16(ga + k2, &As[nxt][tid * 8]);
      GLL16(ga + (size_t)64 * K + k2, &As[nxt][2048 + tid * 8]);
      GLL16(gb + k2, &Bs[nxt][tid * 8]);
      GLL16(gb + (size_t)64 * K + k2, &Bs[nxt][2048 + tid * 8]);
    }
    bf16x8 af[4], bfr[4];
#pragma unroll
    for (int i = 0; i < 4; i++) af[i] = *(const bf16x8*)&As[cur][aoff + i * 16 * BK];
#pragma unroll
    for (int j = 0; j < 4; j++) bfr[j] = *(const bf16x8*)&Bs[cur][boff + j * 16 * BK];
#pragma unroll
    for (int i = 0; i < 4; i++)
#pragma unroll
      for (int j = 0; j < 4; j++)
        acc[i][j] = __builtin_amdgcn_mfma_f32_16x16x32_bf16(af[i], bfr[j], acc[i][j], 0, 0, 0);
    cur = (cur == 2) ? 0 : cur + 1;
    nxt = (nxt == 2) ? 0 : nxt + 1;
  }
  const int crow0 = bm + wr * 64 + lhi * 4, ccol0 = bn + wc * 64 + l15;
#pragma unroll
  for (int i = 0; i < 4; i++)
#pragma unroll
    for (int j = 0; j < 4; j++)
#pragma unroll
      for (int r = 0; r < 4; r++)
        C[(size_t)(crow0 + i * 16 + r) * N + ccol0 + j * 16] = acc[i][j][r];
}

// ---------- causal flash attention v5 (R9 proven: 48 us) ----------
__global__ __launch_bounds__(256, 4) void k_attn(
    const u16* __restrict__ q_bf, const u16* __restrict__ k_bf,
    const u16* __restrict__ vT_bf, u16* __restrict__ att_bf) {
  __shared__ __align__(16) char lds[40960];
  const int bid = blockIdx.x;
  const int g = bid >> 5, g0 = g & 7, gs = g >> 3;
  const int qb = (gs == 0) ? (31 - g0) : (gs == 1) ? g0 : (gs == 2) ? (23 - g0) : (8 + g0);
  const int hb = bid & 31;
  const int h = hb & 15, b = hb >> 4;
  const int kvh = h >> 2;
  const int tid = threadIdx.x, lane = tid & 63, w = tid >> 6;
  const int l15 = lane & 15, lhi = lane >> 4;
  const u16* Qg = q_bf + ((size_t)((b * H_C + h) * T_C) + qb * 64) * 64;
  const u16* Kg = k_bf + ((size_t)((b * KV_C + kvh) * T_C)) * 64;
  const u16* Vg = vT_bf + (size_t)(b * KV_C + kvh) * 64 * T_C;  // [64][T]

  bf16x8 qf[2];
  const int qrow = w * 16 + l15;
#pragma unroll
  for (int kc = 0; kc < 2; kc++)
    qf[kc] = *(const bf16x8*)&Qg[(size_t)qrow * 64 + kc * 32 + lhi * 8];

  f32x4 o[4] = {};
  float m = -1e30f, lsum = 0.f;

  const int nt = qb + 1;
  const int r0 = tid >> 3, j0 = tid & 7;
  const int r1 = r0 + 32;
  const int wb0 = r0 * 128 + ((j0 * 16) ^ ((r0 & 7) << 4));
  const int wb1 = r1 * 128 + ((j0 * 16) ^ ((r1 & 7) << 4));
  char* psb = lds + 0x8000 + w * 0x800;
  const int psw = (l15 & 7) << 4;

  bf16x8 kr0, kr1, vr0, vr1;
  kr0 = *(const bf16x8*)&Kg[(size_t)r0 * 64 + j0 * 8];
  kr1 = *(const bf16x8*)&Kg[(size_t)r1 * 64 + j0 * 8];
  vr0 = *(const bf16x8*)&Vg[(size_t)r0 * T_C + j0 * 8];
  vr1 = *(const bf16x8*)&Vg[(size_t)r1 * T_C + j0 * 8];
  *(bf16x8*)(lds + wb0) = kr0;
  *(bf16x8*)(lds + wb1) = kr1;
  *(bf16x8*)(lds + 0x4000 + wb0) = vr0;
  *(bf16x8*)(lds + 0x4000 + wb1) = vr1;
  __syncthreads();

  for (int it = 0; it < nt; ++it) {
    const int t0 = it * 64;
    const int coff = (it & 1) * 0x2000;
    if (it + 1 < nt) {
      const int t1 = t0 + 64;
      kr0 = *(const bf16x8*)&Kg[(size_t)(t1 + r0) * 64 + j0 * 8];
      kr1 = *(const bf16x8*)&Kg[(size_t)(t1 + r1) * 64 + j0 * 8];
      vr0 = *(const bf16x8*)&Vg[(size_t)r0 * T_C + t1 + j0 * 8];
      vr1 = *(const bf16x8*)&Vg[(size_t)r1 * T_C + t1 + j0 * 8];
    }
    // ---- S^T = K Q^T (swapped operands; q = l15, key = nf*16+lhi*4+r) ----
    bf16x8 kf[4][2];
#pragma unroll
    for (int nf = 0; nf < 4; nf++)
#pragma unroll
      for (int kc = 0; kc < 2; kc++) {
        const int row = nf * 16 + l15;
        kf[nf][kc] = *(const bf16x8*)(lds + coff + row * 128 +
                                      ((kc * 64 + lhi * 16) ^ ((l15 & 7) << 4)));
      }
    f32x4 s[4] = {};
    __builtin_amdgcn_s_setprio(1);
#pragma unroll
    for (int nf = 0; nf < 4; nf++)
#pragma unroll
      for (int kc = 0; kc < 2; kc++)
        s[nf] = __builtin_amdgcn_mfma_f32_16x16x32_bf16(kf[nf][kc], qf[kc], s[nf], 0, 0, 0);
    __builtin_amdgcn_s_setprio(0);
    // ---- causal mask on diagonal tile: key > q ----
    if (it == nt - 1) {
      const int qg = w * 16 + l15;
#pragma unroll
      for (int nf = 0; nf < 4; nf++) {
        const int kb2 = nf * 16 + lhi * 4;
#pragma unroll
        for (int r = 0; r < 4; r++)
          if (kb2 + r > qg) s[nf][r] = -1e30f;
      }
    }
    // ---- online softmax: lane owns q-row; 2-shfl reduce over lhi ----
    float a0 = fmaxf(fmaxf(s[0][0], s[0][1]), fmaxf(s[0][2], s[0][3]));
    float a1 = fmaxf(fmaxf(s[1][0], s[1][1]), fmaxf(s[1][2], s[1][3]));
    float a2 = fmaxf(fmaxf(s[2][0], s[2][1]), fmaxf(s[2][2], s[2][3]));
    float a3 = fmaxf(fmaxf(s[3][0], s[3][1]), fmaxf(s[3][2], s[3][3]));
    float tmax = fmaxf(fmaxf(a0, a1), fmaxf(a2, a3));
    tmax = fmaxf(tmax, __shfl_xor(tmax, 16, 64));
    tmax = fmaxf(tmax, __shfl_xor(tmax, 32, 64));
    if (__any(tmax > m)) {
      float mn = fmaxf(m, tmax);
      float alpha = __builtin_exp2f(m - mn);
      m = mn;
      lsum *= alpha;
      float ar[4];
#pragma unroll
      for (int r = 0; r < 4; r++) ar[r] = __shfl(alpha, lhi * 4 + r, 64);
#pragma unroll
      for (int nf = 0; nf < 4; nf++)
#pragma unroll
        for (int r = 0; r < 4; r++) o[nf][r] *= ar[r];
    }
    // ---- P = exp2(S - m), pack bf16 pairs, 8x ds_write_b32 ----
#pragma unroll
    for (int nf = 0; nf < 4; nf++) {
      float p0 = __builtin_exp2f(s[nf][0] - m);
      float p1 = __builtin_exp2f(s[nf][1] - m);
      float p2 = __builtin_exp2f(s[nf][2] - m);
      float p3 = __builtin_exp2f(s[nf][3] - m);
      lsum += (p0 + p1) + (p2 + p3);
      unsigned lo = cvtpk(p0, p1), hi = cvtpk(p2, p3);
      const int pb = ((nf * 32 + lhi * 8) ^ psw) + l15 * 128;
      *(unsigned*)(psb + pb) = lo;
      *(unsigned*)(psb + pb + 4) = hi;
    }
    asm volatile("s_waitcnt lgkmcnt(0)" ::: "memory");
    __builtin_amdgcn_sched_barrier(0);
    // ---- O += P V ----
    __builtin_amdgcn_s_setprio(1);
#pragma unroll
    for (int kc = 0; kc < 2; kc++) {
      bf16x8 pa = *(const bf16x8*)(psb + l15 * 128 +
                                   ((kc * 64 + lhi * 16) ^ ((l15 & 7) << 4)));
#pragma unroll
      for (int nf = 0; nf < 4; nf++) {
        bf16x8 vf = *(const bf16x8*)(lds + 0x4000 + coff + (nf * 16 + l15) * 128 +
                                     ((kc * 64 + lhi * 16) ^ ((l15 & 7) << 4)));
        o[nf] = __builtin_amdgcn_mfma_f32_16x16x32_bf16(pa, vf, o[nf], 0, 0, 0);
      }
    }
    __builtin_amdgcn_s_setprio(0);
    if (it + 1 < nt) {
      const int noff = ((it + 1) & 1) * 0x2000;
      *(bf16x8*)(lds + noff + wb0) = kr0;
      *(bf16x8*)(lds + noff + wb1) = kr1;
      *(bf16x8*)(lds + 0x4000 + noff + wb0) = vr0;
      *(bf16x8*)(lds + 0x4000 + noff + wb1) = vr1;
    }
    __syncthreads();
  }
  // ---- epilogue: reduce lsum over lhi, redistribute inv to O rows ----
  lsum += __shfl_xor(lsum, 16, 64);
  lsum += __shfl_xor(lsum, 32, 64);
  float inv = 1.0f / lsum;
  float invr[4];
#pragma unroll
  for (int r = 0; r < 4; r++) invr[r] = __shfl(inv, lhi * 4 + r, 64);
  const int trow = qb * 64 + w * 16 + lhi * 4;
  const size_t obase = ((size_t)(b * T_C) + trow) * 1024 + h * 64;
#pragma unroll
  for (int nf = 0; nf < 4; nf++)
#pragma unroll
    for (int r = 0; r < 4; r++)
      att_bf[obase + (size_t)r * 1024 + nf * 16 + l15] = f2bf(o[nf][r] * invr[r]);
}

extern "C" void kernel_launch(void* const* d_in, const int* in_sizes, int n_in,
                              void* d_out, int out_size, void* d_ws, size_t ws_size,
                              hipStream_t stream) {
  const float* x  = (const float*)d_in[0];
  const float* wq = (const float*)d_in[2];
  const float* wk = (const float*)d_in[3];
  const float* wv = (const float*)d_in[4];
  const float* wo = (const float*)d_in[5];
  float* out = (float*)d_out;

  char* ws = (char*)d_ws;
  u16*   xb    = (u16*)(ws);                          //  8 MiB
  u16*   wqkvT = (u16*)(ws + (8ull  << 20));          //  3 MiB
  u16*   woT   = (u16*)(ws + (11ull << 20));          //  2 MiB
  u16*   vT_bf = (u16*)(ws + (13ull << 20));          //  2 MiB
  f32x2* tab   = (f32x2*)(ws + (15ull << 20));        // 512 KiB
  u16*   q_bf  = (u16*)(ws + (37ull << 20));          //  8 MiB
  u16*   k_bf  = (u16*)(ws + (45ull << 20));          //  2 MiB
  u16*   attb  = (u16*)(ws + (49ull << 20));          //  8 MiB

  k_prep<<<6912, 256, 0, stream>>>(x, xb, wq, wk, wv, wo, wqkvT, woT, tab);
  k_gemm_qkv<<<dim3(32, 12), 256, 0, stream>>>(xb, wqkvT, tab, q_bf, k_bf, vT_bf);
  k_attn<<<1024, 256, 0, stream>>>(q_bf, k_bf, vT_bf, attb);
  k_gemm_bt<<<dim3(32, 8), 256, 0, stream>>>(attb, woT, out, 4096, 1024, 1024);
}

// Round 13
// 99.246 us; speedup vs baseline: 2.5705x; 1.0921x over previous
//
#include <hip/hip_runtime.h>
#include <cstdint>

typedef unsigned short u16;
typedef __attribute__((ext_vector_type(2))) float f32x2;
typedef __attribute__((ext_vector_type(4))) float f32x4;
typedef __attribute__((ext_vector_type(8))) short bf16x8;
typedef __attribute__((ext_vector_type(4))) u16 u16x4;

#define B_C 2
#define T_C 2048
#define H_C 16
#define KV_C 4

__device__ __forceinline__ u16 f2bf(float f) {
  unsigned u = __builtin_bit_cast(unsigned, f);
  u = (u + 0x7fffu + ((u >> 16) & 1u)) >> 16;
  return (u16)u;
}

__device__ __forceinline__ unsigned cvtpk(float a, float b) {
  unsigned r;
  asm("v_cvt_pk_bf16_f32 %0, %1, %2" : "=v"(r) : "v"(a), "v"(b));
  return r;
}

#define GLL16(src, dst)                                                     \
  __builtin_amdgcn_global_load_lds(                                         \
      (__attribute__((address_space(1))) void*)(src),                       \
      (__attribute__((address_space(3))) void*)(dst), 16, 0, 0)

// ---------- fused prep: x->bf16, 4 weight transposes, cos/sin table ----------
__global__ void k_prep(const float* __restrict__ x, u16* __restrict__ xb,
                       const float* __restrict__ wq, const float* __restrict__ wk,
                       const float* __restrict__ wv, const float* __restrict__ wo,
                       u16* __restrict__ wqkvT, u16* __restrict__ woT,
                       f32x2* __restrict__ tab) {
  __shared__ float t[32][33];
  const int bid = blockIdx.x, tid = threadIdx.x;
  if (bid < 4096) {
    int i = bid * 256 + tid;
    f32x4 v = *(const f32x4*)(x + (size_t)i * 4);
    u16x4 o;
    o[0] = f2bf(v[0]); o[1] = f2bf(v[1]); o[2] = f2bf(v[2]); o[3] = f2bf(v[3]);
    *(u16x4*)(xb + (size_t)i * 4) = o;
  } else if (bid < 6656) {
    const float* in; u16* out; int N, lb;
    if (bid < 5120)      { in = wq; out = wqkvT;               N = 1024; lb = bid - 4096; }
    else if (bid < 5376) { in = wk; out = wqkvT + 1024 * 1024; N = 256;  lb = bid - 5120; }
    else if (bid < 5632) { in = wv; out = wqkvT + 1280 * 1024; N = 256;  lb = bid - 5376; }
    else                 { in = wo; out = woT;                 N = 1024; lb = bid - 5632; }
    const int kb = (lb & 31) * 32, nb = (lb >> 5) * 32;
    const int tx = tid & 31, ty = tid >> 5;
#pragma unroll
    for (int i = 0; i < 32; i += 8) t[ty + i][tx] = in[(size_t)(kb + ty + i) * N + nb + tx];
    __syncthreads();
#pragma unroll
    for (int i = 0; i < 32; i += 8) out[(size_t)(nb + ty + i) * 1024 + kb + tx] = f2bf(t[tx][ty + i]);
  } else {
    int idx = (bid - 6656) * 256 + tid;  // t*32 + i
    int i = idx & 31, tt = idx >> 5;
    float ang = (float)tt * exp2f(-(float)(2 * i) * (13.28771237954945f / 64.0f));
    float sn, cs; sincosf(ang, &sn, &cs);
    f32x2 v; v.x = cs; v.y = sn;
    tab[idx] = v;
  }
}

// ---------- GEMM1: 64x128 tile, 3-buf counted-vmcnt, fused RoPE epilogue ----------
__global__ __launch_bounds__(256, 3) void k_gemm_qkv(
    const u16* __restrict__ A, const u16* __restrict__ Bt,
    const f32x2* __restrict__ tab,
    u16* __restrict__ qb_, u16* __restrict__ kb_, u16* __restrict__ vT_) {
  constexpr int BK = 32, K = 1024, NT = K / BK;
  __shared__ u16 As[3][64 * BK];
  __shared__ u16 Bs[3][128 * BK];
  const int tid = threadIdx.x;
  const int lane = tid & 63, wid = tid >> 6;
  const int wr = wid >> 1, wc = wid & 1;
  const int l15 = lane & 15, lhi = lane >> 4;
  const int bm = blockIdx.x * 64, bn = blockIdx.y * 128;
  const int srow = tid >> 2, scol = (tid & 3) * 8;
  const u16* ga = A + (size_t)(bm + srow) * K + scol;
  const u16* gb = Bt + (size_t)(bn + srow) * K + scol;
  f32x4 acc[2][4] = {};
  const int aoff = (wr * 32 + l15) * BK + lhi * 8;
  const int boff = (wc * 64 + l15) * BK + lhi * 8;
  // prologue: stage tiles 0,1 (3 loads each)
#pragma unroll
  for (int p = 0; p < 2; p++) {
    GLL16(ga + p * BK, &As[p][tid * 8]);
    GLL16(gb + p * BK, &Bs[p][tid * 8]);
    GLL16(gb + (size_t)64 * K + p * BK, &Bs[p][2048 + tid * 8]);
  }
  int cur = 0, nxt = 2;
  for (int k = 0; k < NT; ++k) {
    if (k + 1 < NT) asm volatile("s_waitcnt vmcnt(3)" ::: "memory");
    else            asm volatile("s_waitcnt vmcnt(0)" ::: "memory");
    __builtin_amdgcn_s_barrier();
    if (k + 2 < NT) {
      const int k2 = (k + 2) * BK;
      GLL16(ga + k2, &As[nxt][tid * 8]);
      GLL16(gb + k2, &Bs[nxt][tid * 8]);
      GLL16(gb + (size_t)64 * K + k2, &Bs[nxt][2048 + tid * 8]);
    }
    bf16x8 af[2], bfr[4];
#pragma unroll
    for (int i = 0; i < 2; i++) af[i] = *(const bf16x8*)&As[cur][aoff + i * 16 * BK];
#pragma unroll
    for (int j = 0; j < 4; j++) bfr[j] = *(const bf16x8*)&Bs[cur][boff + j * 16 * BK];
#pragma unroll
    for (int i = 0; i < 2; i++)
#pragma unroll
      for (int j = 0; j < 4; j++)
        acc[i][j] = __builtin_amdgcn_mfma_f32_16x16x32_bf16(af[i], bfr[j], acc[i][j], 0, 0, 0);
    cur = (cur == 2) ? 0 : cur + 1;
    nxt = (nxt == 2) ? 0 : nxt + 1;
  }
  // ---- fused epilogue ----
  const int crow0 = bm + wr * 32 + lhi * 4;
  const int bsel = (blockIdx.x >= 32) ? 1 : 0;
  const int hg = (bn >> 6) + wc;
  if (blockIdx.y >= 10) {
    u16* dst = vT_ + ((size_t)(bsel * KV_C + (hg - 20)) * 64) * T_C;
#pragma unroll
    for (int j = 0; j < 4; j++) {
      const int d = l15 + j * 16;
#pragma unroll
      for (int i = 0; i < 2; i++) {
        const int t2 = (crow0 + i * 16) & 2047;
        u16x4 pk;
#pragma unroll
        for (int r = 0; r < 4; r++) pk[r] = f2bf(acc[i][j][r]);
        *(u16x4*)&dst[(size_t)d * T_C + t2] = pk;
      }
    }
  } else {
    const bool isq = (blockIdx.y < 8);
    u16* dst = isq ? (qb_ + ((size_t)(bsel * H_C + hg) * T_C) * 64)
                   : (kb_ + ((size_t)(bsel * KV_C + (hg - 16)) * T_C) * 64);
    const float sc = isq ? (0.125f * 1.4426950408889634f) : 1.0f;
    const int par = l15 & 1;
#pragma unroll
    for (int j = 0; j < 4; j++) {
      const int d = l15 + j * 16;
      const int ir = (l15 >> 1) + j * 8;
#pragma unroll
      for (int i = 0; i < 2; i++)
#pragma unroll
        for (int r = 0; r < 4; r++) {
          const int t2 = (crow0 + i * 16 + r) & 2047;
          float v = acc[i][j][r];
          float p = __shfl_xor(v, 1, 64);
          f32x2 cs = tab[t2 * 32 + ir];
          float sgn = par ? cs.y : -cs.y;
          dst[(size_t)t2 * 64 + d] = f2bf((v * cs.x + p * sgn) * sc);
        }
    }
  }
}

// ---------- GEMM2: 64x128 tile, 3-buf counted-vmcnt ----------
__global__ __launch_bounds__(256, 3) void k_gemm_bt(
    const u16* __restrict__ A, const u16* __restrict__ Bt, float* __restrict__ C,
    int M, int N, int K) {
  constexpr int BK = 32;
  __shared__ u16 As[3][64 * BK];
  __shared__ u16 Bs[3][128 * BK];
  const int tid = threadIdx.x;
  const int lane = tid & 63, wid = tid >> 6;
  const int wr = wid >> 1, wc = wid & 1;
  const int l15 = lane & 15, lhi = lane >> 4;
  const int bm = blockIdx.x * 64, bn = blockIdx.y * 128;
  const int srow = tid >> 2, scol = (tid & 3) * 8;
  const u16* ga = A + (size_t)(bm + srow) * K + scol;
  const u16* gb = Bt + (size_t)(bn + srow) * K + scol;
  f32x4 acc[2][4] = {};
  const int aoff = (wr * 32 + l15) * BK + lhi * 8;
  const int boff = (wc * 64 + l15) * BK + lhi * 8;
  const int NT = K / BK;
#pragma unroll
  for (int p = 0; p < 2; p++) {
    GLL16(ga + p * BK, &As[p][tid * 8]);
    GLL16(gb + p * BK, &Bs[p][tid * 8]);
    GLL16(gb + (size_t)64 * K + p * BK, &Bs[p][2048 + tid * 8]);
  }
  int cur = 0, nxt = 2;
  for (int k = 0; k < NT; ++k) {
    if (k + 1 < NT) asm volatile("s_waitcnt vmcnt(3)" ::: "memory");
    else            asm volatile("s_waitcnt vmcnt(0)" ::: "memory");
    __builtin_amdgcn_s_barrier();
    if (k + 2 < NT) {
      const int k2 = (k + 2) * BK;
      GLL16(ga + k2, &As[nxt][tid * 8]);
      GLL16(gb + k2, &Bs[nxt][tid * 8]);
      GLL16(gb + (size_t)64 * K + k2, &Bs[nxt][2048 + tid * 8]);
    }
    bf16x8 af[2], bfr[4];
#pragma unroll
    for (int i = 0; i < 2; i++) af[i] = *(const bf16x8*)&As[cur][aoff + i * 16 * BK];
#pragma unroll
    for (int j = 0; j < 4; j++) bfr[j] = *(const bf16x8*)&Bs[cur][boff + j * 16 * BK];
#pragma unroll
    for (int i = 0; i < 2; i++)
#pragma unroll
      for (int j = 0; j < 4; j++)
        acc[i][j] = __builtin_amdgcn_mfma_f32_16x16x32_bf16(af[i], bfr[j], acc[i][j], 0, 0, 0);
    cur = (cur == 2) ? 0 : cur + 1;
    nxt = (nxt == 2) ? 0 : nxt + 1;
  }
  const int crow0 = bm + wr * 32 + lhi * 4, ccol0 = bn + wc * 64 + l15;
#pragma unroll
  for (int i = 0; i < 2; i++)
#pragma unroll
    for (int j = 0; j < 4; j++)
#pragma unroll
      for (int r = 0; r < 4; r++)
        C[(size_t)(crow0 + i * 16 + r) * N + ccol0 + j * 16] = acc[i][j][r];
}

// ---------- causal flash attention v5 (R9 proven: 47-48 us) ----------
__global__ __launch_bounds__(256, 4) void k_attn(
    const u16* __restrict__ q_bf, const u16* __restrict__ k_bf,
    const u16* __restrict__ vT_bf, u16* __restrict__ att_bf) {
  __shared__ __align__(16) char lds[40960];
  const int bid = blockIdx.x;
  const int g = bid >> 5, g0 = g & 7, gs = g >> 3;
  const int qb = (gs == 0) ? (31 - g0) : (gs == 1) ? g0 : (gs == 2) ? (23 - g0) : (8 + g0);
  const int hb = bid & 31;
  const int h = hb & 15, b = hb >> 4;
  const int kvh = h >> 2;
  const int tid = threadIdx.x, lane = tid & 63, w = tid >> 6;
  const int l15 = lane & 15, lhi = lane >> 4;
  const u16* Qg = q_bf + ((size_t)((b * H_C + h) * T_C) + qb * 64) * 64;
  const u16* Kg = k_bf + ((size_t)((b * KV_C + kvh) * T_C)) * 64;
  const u16* Vg = vT_bf + (size_t)(b * KV_C + kvh) * 64 * T_C;  // [64][T]

  bf16x8 qf[2];
  const int qrow = w * 16 + l15;
#pragma unroll
  for (int kc = 0; kc < 2; kc++)
    qf[kc] = *(const bf16x8*)&Qg[(size_t)qrow * 64 + kc * 32 + lhi * 8];

  f32x4 o[4] = {};
  float m = -1e30f, lsum = 0.f;

  const int nt = qb + 1;
  const int r0 = tid >> 3, j0 = tid & 7;
  const int r1 = r0 + 32;
  const int wb0 = r0 * 128 + ((j0 * 16) ^ ((r0 & 7) << 4));
  const int wb1 = r1 * 128 + ((j0 * 16) ^ ((r1 & 7) << 4));
  char* psb = lds + 0x8000 + w * 0x800;
  const int psw = (l15 & 7) << 4;

  bf16x8 kr0, kr1, vr0, vr1;
  kr0 = *(const bf16x8*)&Kg[(size_t)r0 * 64 + j0 * 8];
  kr1 = *(const bf16x8*)&Kg[(size_t)r1 * 64 + j0 * 8];
  vr0 = *(const bf16x8*)&Vg[(size_t)r0 * T_C + j0 * 8];
  vr1 = *(const bf16x8*)&Vg[(size_t)r1 * T_C + j0 * 8];
  *(bf16x8*)(lds + wb0) = kr0;
  *(bf16x8*)(lds + wb1) = kr1;
  *(bf16x8*)(lds + 0x4000 + wb0) = vr0;
  *(bf16x8*)(lds + 0x4000 + wb1) = vr1;
  __syncthreads();

  for (int it = 0; it < nt; ++it) {
    const int t0 = it * 64;
    const int coff = (it & 1) * 0x2000;
    if (it + 1 < nt) {
      const int t1 = t0 + 64;
      kr0 = *(const bf16x8*)&Kg[(size_t)(t1 + r0) * 64 + j0 * 8];
      kr1 = *(const bf16x8*)&Kg[(size_t)(t1 + r1) * 64 + j0 * 8];
      vr0 = *(const bf16x8*)&Vg[(size_t)r0 * T_C + t1 + j0 * 8];
      vr1 = *(const bf16x8*)&Vg[(size_t)r1 * T_C + t1 + j0 * 8];
    }
    // ---- S^T = K Q^T (swapped operands; q = l15, key = nf*16+lhi*4+r) ----
    bf16x8 kf[4][2];
#pragma unroll
    for (int nf = 0; nf < 4; nf++)
#pragma unroll
      for (int kc = 0; kc < 2; kc++) {
        const int row = nf * 16 + l15;
        kf[nf][kc] = *(const bf16x8*)(lds + coff + row * 128 +
                                      ((kc * 64 + lhi * 16) ^ ((l15 & 7) << 4)));
      }
    f32x4 s[4] = {};
    __builtin_amdgcn_s_setprio(1);
#pragma unroll
    for (int nf = 0; nf < 4; nf++)
#pragma unroll
      for (int kc = 0; kc < 2; kc++)
        s[nf] = __builtin_amdgcn_mfma_f32_16x16x32_bf16(kf[nf][kc], qf[kc], s[nf], 0, 0, 0);
    __builtin_amdgcn_s_setprio(0);
    // ---- causal mask on diagonal tile: key > q ----
    if (it == nt - 1) {
      const int qg = w * 16 + l15;
#pragma unroll
      for (int nf = 0; nf < 4; nf++) {
        const int kb2 = nf * 16 + lhi * 4;
#pragma unroll
        for (int r = 0; r < 4; r++)
          if (kb2 + r > qg) s[nf][r] = -1e30f;
      }
    }
    // ---- online softmax: lane owns q-row; 2-shfl reduce over lhi ----
    float a0 = fmaxf(fmaxf(s[0][0], s[0][1]), fmaxf(s[0][2], s[0][3]));
    float a1 = fmaxf(fmaxf(s[1][0], s[1][1]), fmaxf(s[1][2], s[1][3]));
    float a2 = fmaxf(fmaxf(s[2][0], s[2][1]), fmaxf(s[2][2], s[2][3]));
    float a3 = fmaxf(fmaxf(s[3][0], s[3][1]), fmaxf(s[3][2], s[3][3]));
    float tmax = fmaxf(fmaxf(a0, a1), fmaxf(a2, a3));
    tmax = fmaxf(tmax, __shfl_xor(tmax, 16, 64));
    tmax = fmaxf(tmax, __shfl_xor(tmax, 32, 64));
    if (__any(tmax > m)) {
      float mn = fmaxf(m, tmax);
      float alpha = __builtin_exp2f(m - mn);
      m = mn;
      lsum *= alpha;
      float ar[4];
#pragma unroll
      for (int r = 0; r < 4; r++) ar[r] = __shfl(alpha, lhi * 4 + r, 64);
#pragma unroll
      for (int nf = 0; nf < 4; nf++)
#pragma unroll
        for (int r = 0; r < 4; r++) o[nf][r] *= ar[r];
    }
    // ---- P = exp2(S - m), pack bf16 pairs, 8x ds_write_b32 ----
#pragma unroll
    for (int nf = 0; nf < 4; nf++) {
      float p0 = __builtin_exp2f(s[nf][0] - m);
      float p1 = __builtin_exp2f(s[nf][1] - m);
      float p2 = __builtin_exp2f(s[nf][2] - m);
      float p3 = __builtin_exp2f(s[nf][3] - m);
      lsum += (p0 + p1) + (p2 + p3);
      unsigned lo = cvtpk(p0, p1), hi = cvtpk(p2, p3);
      const int pb = ((nf * 32 + lhi * 8) ^ psw) + l15 * 128;
      *(unsigned*)(psb + pb) = lo;
      *(unsigned*)(psb + pb + 4) = hi;
    }
    asm volatile("s_waitcnt lgkmcnt(0)" ::: "memory");
    __builtin_amdgcn_sched_barrier(0);
    // ---- O += P V ----
    __builtin_amdgcn_s_setprio(1);
#pragma unroll
    for (int kc = 0; kc < 2; kc++) {
      bf16x8 pa = *(const bf16x8*)(psb + l15 * 128 +
                                   ((kc * 64 + lhi * 16) ^ ((l15 & 7) << 4)));
#pragma unroll
      for (int nf = 0; nf < 4; nf++) {
        bf16x8 vf = *(const bf16x8*)(lds + 0x4000 + coff + (nf * 16 + l15) * 128 +
                                     ((kc * 64 + lhi * 16) ^ ((l15 & 7) << 4)));
        o[nf] = __builtin_amdgcn_mfma_f32_16x16x32_bf16(pa, vf, o[nf], 0, 0, 0);
      }
    }
    __builtin_amdgcn_s_setprio(0);
    if (it + 1 < nt) {
      const int noff = ((it + 1) & 1) * 0x2000;
      *(bf16x8*)(lds + noff + wb0) = kr0;
      *(bf16x8*)(lds + noff + wb1) = kr1;
      *(bf16x8*)(lds + 0x4000 + noff + wb0) = vr0;
      *(bf16x8*)(lds + 0x4000 + noff + wb1) = vr1;
    }
    __syncthreads();
  }
  // ---- epilogue: reduce lsum over lhi, redistribute inv to O rows ----
  lsum += __shfl_xor(lsum, 16, 64);
  lsum += __shfl_xor(lsum, 32, 64);
  float inv = 1.0f / lsum;
  float invr[4];
#pragma unroll
  for (int r = 0; r < 4; r++) invr[r] = __shfl(inv, lhi * 4 + r, 64);
  const int trow = qb * 64 + w * 16 + lhi * 4;
  const size_t obase = ((size_t)(b * T_C) + trow) * 1024 + h * 64;
#pragma unroll
  for (int nf = 0; nf < 4; nf++)
#pragma unroll
    for (int r = 0; r < 4; r++)
      att_bf[obase + (size_t)r * 1024 + nf * 16 + l15] = f2bf(o[nf][r] * invr[r]);
}

extern "C" void kernel_launch(void* const* d_in, const int* in_sizes, int n_in,
                              void* d_out, int out_size, void* d_ws, size_t ws_size,
                              hipStream_t stream) {
  const float* x  = (const float*)d_in[0];
  const float* wq = (const float*)d_in[2];
  const float* wk = (const float*)d_in[3];
  const float* wv = (const float*)d_in[4];
  const float* wo = (const float*)d_in[5];
  float* out = (float*)d_out;

  char* ws = (char*)d_ws;
  u16*   xb    = (u16*)(ws);                          //  8 MiB
  u16*   wqkvT = (u16*)(ws + (8ull  << 20));          //  3 MiB
  u16*   woT   = (u16*)(ws + (11ull << 20));          //  2 MiB
  u16*   vT_bf = (u16*)(ws + (13ull << 20));          //  2 MiB
  f32x2* tab   = (f32x2*)(ws + (15ull << 20));        // 512 KiB
  u16*   q_bf  = (u16*)(ws + (37ull << 20));          //  8 MiB
  u16*   k_bf  = (u16*)(ws + (45ull << 20));          //  2 MiB
  u16*   attb  = (u16*)(ws + (49ull << 20));          //  8 MiB

  k_prep<<<6912, 256, 0, stream>>>(x, xb, wq, wk, wv, wo, wqkvT, woT, tab);
  k_gemm_qkv<<<dim3(64, 12), 256, 0, stream>>>(xb, wqkvT, tab, q_bf, k_bf, vT_bf);
  k_attn<<<1024, 256, 0, stream>>>(q_bf, k_bf, vT_bf, attb);
  k_gemm_bt<<<dim3(64, 8), 256, 0, stream>>>(attb, woT, out, 4096, 1024, 1024);
}